// Round 5
// baseline (478.296 us; speedup 1.0000x reference)
//
#include <hip/hip_runtime.h>
#include <hip/hip_fp16.h>

// ConformalGCN: 2-layer GCN, N=100000, E=1600000 (+self loops).
// R4: (a) revert gemm2 fusion (R3 regression: barrier-coupled latency+VALU
//     phases, 138us), (b) half-wave edge pairing in csr_agg: lane w holds
//     feats (2w,2w+1) as float2; half 0 = even edges, half 1 = odd edges ->
//     zero duplicate reads, 2x MLP, no LDS. fp16 rows, fp32 accumulation.

#define IN_F  128
#define HID_F 64
#define OUT_F 96

__device__ __forceinline__ float2 unpack2(unsigned u) {
    __half2 h = *reinterpret_cast<__half2*>(&u);
    return __half22float2(h);
}
__device__ __forceinline__ unsigned f2h2(float lo, float hi) {
    __half2 h = __floats2half2_rn(lo, hi);
    return *reinterpret_cast<unsigned*>(&h);
}

__global__ __launch_bounds__(256) void zero_deg(int* __restrict__ deg, int n) {
    for (int i = blockIdx.x * 256 + threadIdx.x; i < n; i += gridDim.x * 256)
        deg[i] = 0;
}

__global__ __launch_bounds__(256) void count_deg(const int* __restrict__ dst,
                                                 int* __restrict__ deg, int E) {
    for (int e = blockIdx.x * 256 + threadIdx.x; e < E; e += gridDim.x * 256)
        atomicAdd(&deg[dst[e]], 1);
}

// ---- hierarchical exclusive prefix sum over deg[n] (1024 elems/block) ----
__global__ __launch_bounds__(256) void scan_blocks(const int* __restrict__ deg,
                                                   int* __restrict__ pre,
                                                   int* __restrict__ bsum, int n) {
    __shared__ int lds[256];
    const int t = threadIdx.x;
    const int base = blockIdx.x * 1024 + t * 4;
    int v0 = (base + 0 < n) ? deg[base + 0] : 0;
    int v1 = (base + 1 < n) ? deg[base + 1] : 0;
    int v2 = (base + 2 < n) ? deg[base + 2] : 0;
    int v3 = (base + 3 < n) ? deg[base + 3] : 0;
    int s = v0 + v1 + v2 + v3;
    lds[t] = s;
    __syncthreads();
    for (int off = 1; off < 256; off <<= 1) {
        int add = (t >= off) ? lds[t - off] : 0;
        __syncthreads();
        lds[t] += add;
        __syncthreads();
    }
    int e = lds[t] - s;
    if (base + 0 < n) pre[base + 0] = e;
    e += v0;
    if (base + 1 < n) pre[base + 1] = e;
    e += v1;
    if (base + 2 < n) pre[base + 2] = e;
    e += v2;
    if (base + 3 < n) pre[base + 3] = e;
    if (t == 255) bsum[blockIdx.x] = lds[255];
}

__global__ __launch_bounds__(256) void scan_bsums(const int* __restrict__ bsum,
                                                  int* __restrict__ boffs, int nb) {
    __shared__ int lds[256];
    const int t = threadIdx.x;
    int v = (t < nb) ? bsum[t] : 0;
    lds[t] = v;
    __syncthreads();
    for (int off = 1; off < 256; off <<= 1) {
        int add = (t >= off) ? lds[t - off] : 0;
        __syncthreads();
        lds[t] += add;
        __syncthreads();
    }
    boffs[t] = lds[t] - v;
}

__global__ __launch_bounds__(256) void add_offsets(const int* __restrict__ pre,
                                                   const int* __restrict__ boffs,
                                                   const int* __restrict__ deg,
                                                   int* __restrict__ rowptr,
                                                   int* __restrict__ writepos,
                                                   float* __restrict__ dinv,
                                                   int n, int E) {
    for (int i = blockIdx.x * 256 + threadIdx.x; i < n; i += gridDim.x * 256) {
        int r = pre[i] + boffs[i >> 10];
        rowptr[i] = r;
        writepos[i] = r;
        dinv[i] = rsqrtf((float)(deg[i] + 1));   // +1 self loop
        if (i == 0) rowptr[n] = E;
    }
}

// csr_src[pos] = src   (4B record; weight folded into prescaled rows)
__global__ __launch_bounds__(256) void fill_csr(const int* __restrict__ src,
                                                const int* __restrict__ dst,
                                                int* __restrict__ writepos,
                                                int* __restrict__ csr_src, int E) {
    for (int e = blockIdx.x * 256 + threadIdx.x; e < E; e += gridDim.x * 256) {
        int pos = atomicAdd(&writepos[dst[e]], 1);
        csr_src[pos] = src[e];
    }
}

// hs[row] = fp16x2-packed( dinv[row] * (x[row] @ W1) ).  Wave per row, lane=col.
__global__ __launch_bounds__(256) void gemm1(const float* __restrict__ x,
                                             const float* __restrict__ W1,
                                             const float* __restrict__ dinv,
                                             unsigned* __restrict__ hs, int n) {
    __shared__ float w[IN_F * HID_F];   // 32 KiB
    __shared__ float xs[4][IN_F];
    for (int i = threadIdx.x; i < IN_F * HID_F; i += 256) w[i] = W1[i];
    __syncthreads();
    const int wave = threadIdx.x >> 6, lane = threadIdx.x & 63;
    for (int row = blockIdx.x * 4 + wave; row < n; row += gridDim.x * 4) {
        float2 v = *(const float2*)(x + (size_t)row * IN_F + lane * 2);
        xs[wave][lane * 2]     = v.x;
        xs[wave][lane * 2 + 1] = v.y;
        float acc = 0.f;
#pragma unroll 8
        for (int k = 0; k < IN_F; ++k)
            acc = fmaf(xs[wave][k], w[k * HID_F + lane], acc);
        acc *= dinv[row];
        float other = __shfl_xor(acc, 1);      // partner feature
        if (!(lane & 1))                       // even lane: feats (l,l+1) -> word l/2
            hs[(size_t)row * 32 + (lane >> 1)] = f2h2(acc, other);
    }
}

// One wave per node, 4 nodes/block.  Lane w of each half holds feats
// (2w, 2w+1) as float2; half 0 sums even-index edges, half 1 odd-index.
// Cross-half merge via shfl_xor(32).  LAYER 1: bias+relu+prescale -> fp16.
// LAYER 2: plain -> fp32 a2 (gemm2 is standalone).
template <int LAYER>
__global__ __launch_bounds__(256) void csr_agg(const int* __restrict__ rowptr,
                                               const int* __restrict__ csr_src,
                                               const float* __restrict__ dinv,
                                               const unsigned* __restrict__ hs,
                                               const float* __restrict__ b1,
                                               unsigned* __restrict__ hs2,
                                               float* __restrict__ a2, int n) {
    const int node = blockIdx.x * 4 + (threadIdx.x >> 6);
    if (node >= n) return;
    const int lane = threadIdx.x & 63;
    const int wrd  = lane & 31;
    const int half = lane >> 5;
    const int beg = rowptr[node], end = rowptr[node + 1];
    const float dn = dinv[node];

    float ax = 0.f, ay = 0.f;
    if (half == 0) {                                   // self loop, count once
        float2 s = unpack2(hs[(size_t)node * 32 + wrd]);
        ax = s.x; ay = s.y;
    }
    int p = beg;
    for (; p + 16 <= end; p += 16) {                   // 16 edges/iter, 8 per half
        int s0 = csr_src[p + half +  0];
        int s1 = csr_src[p + half +  2];
        int s2 = csr_src[p + half +  4];
        int s3 = csr_src[p + half +  6];
        int s4 = csr_src[p + half +  8];
        int s5 = csr_src[p + half + 10];
        int s6 = csr_src[p + half + 12];
        int s7 = csr_src[p + half + 14];
        unsigned u0 = hs[(size_t)s0 * 32 + wrd];
        unsigned u1 = hs[(size_t)s1 * 32 + wrd];
        unsigned u2 = hs[(size_t)s2 * 32 + wrd];
        unsigned u3 = hs[(size_t)s3 * 32 + wrd];
        unsigned u4 = hs[(size_t)s4 * 32 + wrd];
        unsigned u5 = hs[(size_t)s5 * 32 + wrd];
        unsigned u6 = hs[(size_t)s6 * 32 + wrd];
        unsigned u7 = hs[(size_t)s7 * 32 + wrd];
        float2 v0 = unpack2(u0), v1 = unpack2(u1), v2 = unpack2(u2), v3 = unpack2(u3);
        float2 v4 = unpack2(u4), v5 = unpack2(u5), v6 = unpack2(u6), v7 = unpack2(u7);
        ax += v0.x; ay += v0.y;  ax += v1.x; ay += v1.y;
        ax += v2.x; ay += v2.y;  ax += v3.x; ay += v3.y;
        ax += v4.x; ay += v4.y;  ax += v5.x; ay += v5.y;
        ax += v6.x; ay += v6.y;  ax += v7.x; ay += v7.y;
    }
    for (; p + 2 <= end; p += 2) {                     // pairs
        int s = csr_src[p + half];
        float2 v = unpack2(hs[(size_t)s * 32 + wrd]);
        ax += v.x; ay += v.y;
    }
    if (p < end && half == 0) {                        // odd remainder
        int s = csr_src[p];
        float2 v = unpack2(hs[(size_t)s * 32 + wrd]);
        ax += v.x; ay += v.y;
    }
    ax += __shfl_xor(ax, 32);                          // merge halves
    ay += __shfl_xor(ay, 32);

    if (LAYER == 1) {
        float2 bb = *(const float2*)(b1 + 2 * wrd);
        float vx = fmaxf(fmaf(dn, ax, bb.x), 0.f) * dn;   // relu(a1+b1), prescale
        float vy = fmaxf(fmaf(dn, ay, bb.y), 0.f) * dn;
        if (half == 0)
            hs2[(size_t)node * 32 + wrd] = f2h2(vx, vy);
    } else {
        if (half == 0)
            *(float2*)(a2 + (size_t)node * HID_F + 2 * wrd) =
                make_float2(dn * ax, dn * ay);
    }
}

// out[n][96] = a2[n][64] @ W2[64][96] + b2
__global__ __launch_bounds__(256) void gemm2(const float* __restrict__ a2,
                                             const float* __restrict__ W2,
                                             const float* __restrict__ b2,
                                             float* __restrict__ out, int n) {
    __shared__ float w[HID_F * OUT_F];  // 24 KiB
    __shared__ float bs[OUT_F];
    for (int i = threadIdx.x; i < HID_F * OUT_F; i += 256) w[i] = W2[i];
    for (int i = threadIdx.x; i < OUT_F; i += 256) bs[i] = b2[i];
    __syncthreads();
    int total = n * OUT_F;
    for (int idx = blockIdx.x * 256 + threadIdx.x; idx < total; idx += gridDim.x * 256) {
        int r = idx / OUT_F, j = idx - r * OUT_F;
        const float* a = a2 + (size_t)r * HID_F;
        float acc = bs[j];
#pragma unroll
        for (int k = 0; k < HID_F; ++k)
            acc = fmaf(a[k], w[k * OUT_F + j], acc);
        out[idx] = acc;
    }
}

extern "C" void kernel_launch(void* const* d_in, const int* in_sizes, int n_in,
                              void* d_out, int out_size, void* d_ws, size_t ws_size,
                              hipStream_t stream) {
    const float* x  = (const float*)d_in[0];
    const int*   ei = (const int*)d_in[1];
    const float* W1 = (const float*)d_in[2];
    const float* b1 = (const float*)d_in[3];
    const float* W2 = (const float*)d_in[4];
    const float* b2 = (const float*)d_in[5];
    float* out = (float*)d_out;

    const int n = in_sizes[0] / IN_F;     // 100000
    const int E = in_sizes[1] / 2;        // 1600000
    const int* src = ei;
    const int* dst = ei + E;
    const int NB = (n + 1023) / 1024;     // scan blocks (98)
    const int nquad = (n + 3) / 4;        // 25000

    char* ws = (char*)d_ws;
    size_t off = 0;
    auto alloc = [&](size_t bytes) { void* p = ws + off; off = (off + bytes + 255) & ~(size_t)255; return p; };
    int*      deg      = (int*)alloc((size_t)n * 4);
    float*    dinv     = (float*)alloc((size_t)n * 4);
    int*      pre      = (int*)alloc((size_t)n * 4);
    int*      rowptr   = (int*)alloc((size_t)(n + 1) * 4);
    int*      writepos = (int*)alloc((size_t)n * 4);
    int*      bsum     = (int*)alloc(256 * 4);
    int*      boffs    = (int*)alloc(256 * 4);
    int*      csr_src  = (int*)alloc((size_t)E * 4);
    unsigned* hs       = (unsigned*)alloc((size_t)n * 32 * 4);
    unsigned* hs2      = (unsigned*)alloc((size_t)n * 32 * 4);
    float*    a2       = (float*)alloc((size_t)n * HID_F * 4);

    zero_deg   <<<512, 256, 0, stream>>>(deg, n);
    count_deg  <<<2048, 256, 0, stream>>>(dst, deg, E);
    scan_blocks<<<NB, 256, 0, stream>>>(deg, pre, bsum, n);
    scan_bsums <<<1, 256, 0, stream>>>(bsum, boffs, NB);
    add_offsets<<<512, 256, 0, stream>>>(pre, boffs, deg, rowptr, writepos, dinv, n, E);
    fill_csr   <<<2048, 256, 0, stream>>>(src, dst, writepos, csr_src, E);

    gemm1      <<<2048, 256, 0, stream>>>(x, W1, dinv, hs, n);
    csr_agg<1> <<<nquad, 256, 0, stream>>>(rowptr, csr_src, dinv, hs, b1, hs2, NULL, n);
    csr_agg<2> <<<nquad, 256, 0, stream>>>(rowptr, csr_src, dinv, hs2, NULL, NULL, a2, n);
    gemm2      <<<2048, 256, 0, stream>>>(a2, W2, b2, out, n);
}

// Round 6
// 317.290 us; speedup vs baseline: 1.5074x; 1.5074x over previous
//
#include <hip/hip_runtime.h>
#include <hip/hip_fp16.h>

// ConformalGCN: 2-layer GCN, N=100000, E=1600000 (+self loops).
// R5: CSR build rewritten as 2-pass radix partition (R4 showed the random
//     scatter pays 64B line-writeback per 4B record: WRITE_SIZE ~107MB).
//     bucket = dst>>8 (391 buckets x 256 nodes). Pass1: chunk histograms ->
//     global scan -> private contiguous runs -> atomic-free-ish partition.
//     Pass2: per-bucket LDS build emits rowptr+dinv+coalesced CSR.
//     gemm1 / csr_agg (half-wave fp16 pairing) / gemm2 unchanged from R4.

#define IN_F  128
#define HID_F 64
#define OUT_F 96
#define CHUNK 4096
#define MAXB  8192

__device__ __forceinline__ float2 unpack2(unsigned u) {
    __half2 h = *reinterpret_cast<__half2*>(&u);
    return __half22float2(h);
}
__device__ __forceinline__ unsigned f2h2(float lo, float hi) {
    __half2 h = __floats2half2_rn(lo, hi);
    return *reinterpret_cast<unsigned*>(&h);
}

// ---- pass 1a: per-chunk bucket histograms (bucket-major layout) ----
__global__ __launch_bounds__(256) void hist_chunks(const int* __restrict__ dst,
                                                   int* __restrict__ hist,
                                                   int E, int nbuck, int nchunk) {
    __shared__ int cnt[512];
    for (int i = threadIdx.x; i < nbuck; i += 256) cnt[i] = 0;
    __syncthreads();
    const int base = blockIdx.x * CHUNK;
    const int lim = min(base + CHUNK, E);
    for (int e = base + threadIdx.x; e < lim; e += 256)
        atomicAdd(&cnt[dst[e] >> 8], 1);
    __syncthreads();
    for (int b = threadIdx.x; b < nbuck; b += 256)
        hist[b * nchunk + blockIdx.x] = cnt[b];
}

// ---- hierarchical exclusive prefix sum (1024 elems/block) ----
__global__ __launch_bounds__(256) void scan_blocks(const int* __restrict__ in,
                                                   int* __restrict__ pre,
                                                   int* __restrict__ bsum, int m) {
    __shared__ int lds[256];
    const int t = threadIdx.x;
    const int base = blockIdx.x * 1024 + t * 4;
    int v0 = (base + 0 < m) ? in[base + 0] : 0;
    int v1 = (base + 1 < m) ? in[base + 1] : 0;
    int v2 = (base + 2 < m) ? in[base + 2] : 0;
    int v3 = (base + 3 < m) ? in[base + 3] : 0;
    int s = v0 + v1 + v2 + v3;
    lds[t] = s;
    __syncthreads();
    for (int off = 1; off < 256; off <<= 1) {
        int add = (t >= off) ? lds[t - off] : 0;
        __syncthreads();
        lds[t] += add;
        __syncthreads();
    }
    int e = lds[t] - s;
    if (base + 0 < m) pre[base + 0] = e;
    e += v0;
    if (base + 1 < m) pre[base + 1] = e;
    e += v1;
    if (base + 2 < m) pre[base + 2] = e;
    e += v2;
    if (base + 3 < m) pre[base + 3] = e;
    if (t == 255) bsum[blockIdx.x] = lds[255];
}

__global__ __launch_bounds__(256) void scan_bsums(const int* __restrict__ bsum,
                                                  int* __restrict__ boffs, int nb) {
    __shared__ int lds[256];
    const int t = threadIdx.x;
    int v = (t < nb) ? bsum[t] : 0;
    lds[t] = v;
    __syncthreads();
    for (int off = 1; off < 256; off <<= 1) {
        int add = (t >= off) ? lds[t - off] : 0;
        __syncthreads();
        lds[t] += add;
        __syncthreads();
    }
    boffs[t] = lds[t] - v;
}

__global__ __launch_bounds__(256) void scan_add(int* __restrict__ pre,
                                                const int* __restrict__ boffs, int m) {
    for (int i = blockIdx.x * 256 + threadIdx.x; i < m; i += gridDim.x * 256)
        pre[i] += boffs[i >> 10];
}

// ---- pass 1b: partition edges into bucket-grouped runs, 4B records ----
// record = (src << 8) | (dst & 255);  src < 2^24 required (n = 100000 ok).
__global__ __launch_bounds__(256) void partition(const int* __restrict__ src,
                                                 const int* __restrict__ dst,
                                                 const int* __restrict__ offs,
                                                 unsigned* __restrict__ part,
                                                 int E, int nbuck, int nchunk) {
    __shared__ int off[512];
    for (int b = threadIdx.x; b < nbuck; b += 256)
        off[b] = offs[b * nchunk + blockIdx.x];
    __syncthreads();
    const int base = blockIdx.x * CHUNK;
    const int lim = min(base + CHUNK, E);
    for (int e = base + threadIdx.x; e < lim; e += 256) {
        int d = dst[e], s = src[e];
        int pos = atomicAdd(&off[d >> 8], 1);
        part[pos] = ((unsigned)s << 8) | (unsigned)(d & 255);
    }
}

// ---- pass 2: per-bucket CSR finalize: rowptr, dinv, coalesced csr_src ----
__global__ __launch_bounds__(256) void build_bucket(const unsigned* __restrict__ part,
                                                    const int* __restrict__ offs,
                                                    int* __restrict__ csr_src,
                                                    int* __restrict__ rowptr,
                                                    float* __restrict__ dinv,
                                                    int n, int E, int nbuck, int nchunk) {
    __shared__ int cnt[256], sc[256], off[256];
    __shared__ int stage[MAXB];
    const int b = blockIdx.x;
    const int t = threadIdx.x;
    const int bstart = offs[b * nchunk];
    const int bend = (b + 1 < nbuck) ? offs[(b + 1) * nchunk] : E;
    const int bsize = bend - bstart;
    const int nodebase = b << 8;
    const int nnodes = min(256, n - nodebase);

    cnt[t] = 0;
    __syncthreads();
    for (int i = bstart + t; i < bend; i += 256)
        atomicAdd(&cnt[part[i] & 255u], 1);
    __syncthreads();
    const int deg = cnt[t];
    sc[t] = deg;
    __syncthreads();
    for (int o = 1; o < 256; o <<= 1) {
        int add = (t >= o) ? sc[t - o] : 0;
        __syncthreads();
        sc[t] += add;
        __syncthreads();
    }
    const int excl = sc[t] - deg;
    if (t < nnodes) {
        rowptr[nodebase + t] = bstart + excl;
        dinv[nodebase + t] = rsqrtf((float)(deg + 1));   // +1 self loop
    }
    if (b == 0 && t == 0) rowptr[n] = E;
    off[t] = excl;
    __syncthreads();

    if (bsize <= MAXB) {
        for (int i = bstart + t; i < bend; i += 256) {
            unsigned r = part[i];
            int pos = atomicAdd(&off[r & 255u], 1);
            stage[pos] = (int)(r >> 8);
        }
        __syncthreads();
        for (int i = t; i < bsize; i += 256)
            csr_src[bstart + i] = stage[i];
    } else {   // safety fallback (never expected at avg bucket ~4090)
        for (int i = bstart + t; i < bend; i += 256) {
            unsigned r = part[i];
            int pos = atomicAdd(&off[r & 255u], 1);
            csr_src[bstart + pos] = (int)(r >> 8);
        }
    }
}

// hs[row] = fp16x2-packed( dinv[row] * (x[row] @ W1) ).  Wave per row, lane=col.
__global__ __launch_bounds__(256) void gemm1(const float* __restrict__ x,
                                             const float* __restrict__ W1,
                                             const float* __restrict__ dinv,
                                             unsigned* __restrict__ hs, int n) {
    __shared__ float w[IN_F * HID_F];   // 32 KiB
    __shared__ float xs[4][IN_F];
    for (int i = threadIdx.x; i < IN_F * HID_F; i += 256) w[i] = W1[i];
    __syncthreads();
    const int wave = threadIdx.x >> 6, lane = threadIdx.x & 63;
    for (int row = blockIdx.x * 4 + wave; row < n; row += gridDim.x * 4) {
        float2 v = *(const float2*)(x + (size_t)row * IN_F + lane * 2);
        xs[wave][lane * 2]     = v.x;
        xs[wave][lane * 2 + 1] = v.y;
        float acc = 0.f;
#pragma unroll 8
        for (int k = 0; k < IN_F; ++k)
            acc = fmaf(xs[wave][k], w[k * HID_F + lane], acc);
        acc *= dinv[row];
        float other = __shfl_xor(acc, 1);      // partner feature
        if (!(lane & 1))                       // even lane: feats (l,l+1) -> word l/2
            hs[(size_t)row * 32 + (lane >> 1)] = f2h2(acc, other);
    }
}

// One wave per node, 4 nodes/block.  Lane w of each half holds feats
// (2w, 2w+1) as float2; half 0 sums even-index edges, half 1 odd-index.
// Cross-half merge via shfl_xor(32).  LAYER 1: bias+relu+prescale -> fp16.
// LAYER 2: plain -> fp32 a2 (gemm2 standalone).
template <int LAYER>
__global__ __launch_bounds__(256) void csr_agg(const int* __restrict__ rowptr,
                                               const int* __restrict__ csr_src,
                                               const float* __restrict__ dinv,
                                               const unsigned* __restrict__ hs,
                                               const float* __restrict__ b1,
                                               unsigned* __restrict__ hs2,
                                               float* __restrict__ a2, int n) {
    const int node = blockIdx.x * 4 + (threadIdx.x >> 6);
    if (node >= n) return;
    const int lane = threadIdx.x & 63;
    const int wrd  = lane & 31;
    const int half = lane >> 5;
    const int beg = rowptr[node], end = rowptr[node + 1];
    const float dn = dinv[node];

    float ax = 0.f, ay = 0.f;
    if (half == 0) {                                   // self loop, count once
        float2 s = unpack2(hs[(size_t)node * 32 + wrd]);
        ax = s.x; ay = s.y;
    }
    int p = beg;
    for (; p + 16 <= end; p += 16) {                   // 16 edges/iter, 8 per half
        int s0 = csr_src[p + half +  0];
        int s1 = csr_src[p + half +  2];
        int s2 = csr_src[p + half +  4];
        int s3 = csr_src[p + half +  6];
        int s4 = csr_src[p + half +  8];
        int s5 = csr_src[p + half + 10];
        int s6 = csr_src[p + half + 12];
        int s7 = csr_src[p + half + 14];
        unsigned u0 = hs[(size_t)s0 * 32 + wrd];
        unsigned u1 = hs[(size_t)s1 * 32 + wrd];
        unsigned u2 = hs[(size_t)s2 * 32 + wrd];
        unsigned u3 = hs[(size_t)s3 * 32 + wrd];
        unsigned u4 = hs[(size_t)s4 * 32 + wrd];
        unsigned u5 = hs[(size_t)s5 * 32 + wrd];
        unsigned u6 = hs[(size_t)s6 * 32 + wrd];
        unsigned u7 = hs[(size_t)s7 * 32 + wrd];
        float2 v0 = unpack2(u0), v1 = unpack2(u1), v2 = unpack2(u2), v3 = unpack2(u3);
        float2 v4 = unpack2(u4), v5 = unpack2(u5), v6 = unpack2(u6), v7 = unpack2(u7);
        ax += v0.x; ay += v0.y;  ax += v1.x; ay += v1.y;
        ax += v2.x; ay += v2.y;  ax += v3.x; ay += v3.y;
        ax += v4.x; ay += v4.y;  ax += v5.x; ay += v5.y;
        ax += v6.x; ay += v6.y;  ax += v7.x; ay += v7.y;
    }
    for (; p + 2 <= end; p += 2) {                     // pairs
        int s = csr_src[p + half];
        float2 v = unpack2(hs[(size_t)s * 32 + wrd]);
        ax += v.x; ay += v.y;
    }
    if (p < end && half == 0) {                        // odd remainder
        int s = csr_src[p];
        float2 v = unpack2(hs[(size_t)s * 32 + wrd]);
        ax += v.x; ay += v.y;
    }
    ax += __shfl_xor(ax, 32);                          // merge halves
    ay += __shfl_xor(ay, 32);

    if (LAYER == 1) {
        float2 bb = *(const float2*)(b1 + 2 * wrd);
        float vx = fmaxf(fmaf(dn, ax, bb.x), 0.f) * dn;   // relu(a1+b1), prescale
        float vy = fmaxf(fmaf(dn, ay, bb.y), 0.f) * dn;
        if (half == 0)
            hs2[(size_t)node * 32 + wrd] = f2h2(vx, vy);
    } else {
        if (half == 0)
            *(float2*)(a2 + (size_t)node * HID_F + 2 * wrd) =
                make_float2(dn * ax, dn * ay);
    }
}

// out[n][96] = a2[n][64] @ W2[64][96] + b2
__global__ __launch_bounds__(256) void gemm2(const float* __restrict__ a2,
                                             const float* __restrict__ W2,
                                             const float* __restrict__ b2,
                                             float* __restrict__ out, int n) {
    __shared__ float w[HID_F * OUT_F];  // 24 KiB
    __shared__ float bs[OUT_F];
    for (int i = threadIdx.x; i < HID_F * OUT_F; i += 256) w[i] = W2[i];
    for (int i = threadIdx.x; i < OUT_F; i += 256) bs[i] = b2[i];
    __syncthreads();
    int total = n * OUT_F;
    for (int idx = blockIdx.x * 256 + threadIdx.x; idx < total; idx += gridDim.x * 256) {
        int r = idx / OUT_F, j = idx - r * OUT_F;
        const float* a = a2 + (size_t)r * HID_F;
        float acc = bs[j];
#pragma unroll
        for (int k = 0; k < HID_F; ++k)
            acc = fmaf(a[k], w[k * OUT_F + j], acc);
        out[idx] = acc;
    }
}

extern "C" void kernel_launch(void* const* d_in, const int* in_sizes, int n_in,
                              void* d_out, int out_size, void* d_ws, size_t ws_size,
                              hipStream_t stream) {
    const float* x  = (const float*)d_in[0];
    const int*   ei = (const int*)d_in[1];
    const float* W1 = (const float*)d_in[2];
    const float* b1 = (const float*)d_in[3];
    const float* W2 = (const float*)d_in[4];
    const float* b2 = (const float*)d_in[5];
    float* out = (float*)d_out;

    const int n = in_sizes[0] / IN_F;          // 100000
    const int E = in_sizes[1] / 2;             // 1600000
    const int* src = ei;
    const int* dst = ei + E;
    const int nbuck  = (n + 255) >> 8;         // 391
    const int nchunk = (E + CHUNK - 1) / CHUNK;// 391
    const int M = nbuck * nchunk;              // 152881
    const int NBS = (M + 1023) / 1024;         // scan blocks (150)
    const int nquad = (n + 3) / 4;             // 25000

    char* ws = (char*)d_ws;
    size_t off = 0;
    auto alloc = [&](size_t bytes) { void* p = ws + off; off = (off + bytes + 255) & ~(size_t)255; return p; };
    int*      hist    = (int*)alloc((size_t)M * 4);
    int*      offs    = (int*)alloc((size_t)M * 4);    // scanned (in-place via scan_add)
    int*      bsum    = (int*)alloc(256 * 4);
    int*      boffs   = (int*)alloc(256 * 4);
    unsigned* part    = (unsigned*)alloc((size_t)E * 4);
    int*      csr_src = (int*)alloc((size_t)E * 4);
    int*      rowptr  = (int*)alloc((size_t)(n + 1) * 4);
    float*    dinv    = (float*)alloc((size_t)n * 4);
    unsigned* hs      = (unsigned*)alloc((size_t)n * 32 * 4);
    unsigned* hs2     = (unsigned*)alloc((size_t)n * 32 * 4);
    float*    a2      = (float*)alloc((size_t)n * HID_F * 4);

    // CSR build: histogram -> scan -> partition -> per-bucket finalize
    hist_chunks <<<nchunk, 256, 0, stream>>>(dst, hist, E, nbuck, nchunk);
    scan_blocks <<<NBS, 256, 0, stream>>>(hist, offs, bsum, M);
    scan_bsums  <<<1, 256, 0, stream>>>(bsum, boffs, NBS);
    scan_add    <<<512, 256, 0, stream>>>(offs, boffs, M);
    partition   <<<nchunk, 256, 0, stream>>>(src, dst, offs, part, E, nbuck, nchunk);
    build_bucket<<<nbuck, 256, 0, stream>>>(part, offs, csr_src, rowptr, dinv,
                                            n, E, nbuck, nchunk);

    // network
    gemm1      <<<2048, 256, 0, stream>>>(x, W1, dinv, hs, n);
    csr_agg<1> <<<nquad, 256, 0, stream>>>(rowptr, csr_src, dinv, hs, b1, hs2, NULL, n);
    csr_agg<2> <<<nquad, 256, 0, stream>>>(rowptr, csr_src, dinv, hs2, NULL, NULL, a2, n);
    gemm2      <<<2048, 256, 0, stream>>>(a2, W2, b2, out, n);
}

// Round 7
// 250.019 us; speedup vs baseline: 1.9130x; 1.2691x over previous
//
#include <hip/hip_runtime.h>
#include <hip/hip_fp16.h>

// ConformalGCN: 2-layer GCN, N=100000, E=1600000 (+self loops).
// R6: gemm1/gemm2 were LDS-pipe-bound (2 ds_reads per fma, VALU 33%).
//     Both rewritten around v_dot2_f32_f16 (half2 packed operands, fp32
//     accum): gemm1 = 2 rows/wave amortizing the w-read; gemm2 = 256-row
//     fp16 tile in LDS (csr_agg<2> now emits packed fp16 a2).
//     CSR radix-partition build (R5) and csr_agg gather (R4) unchanged.

#define IN_F  128
#define HID_F 64
#define OUT_F 96
#define CHUNK 4096
#define MAXB  8192

typedef _Float16 f16x2 __attribute__((ext_vector_type(2)));

__device__ __forceinline__ float2 unpack2(unsigned u) {
    __half2 h = *reinterpret_cast<__half2*>(&u);
    return __half22float2(h);
}
__device__ __forceinline__ unsigned f2h2(float lo, float hi) {
    __half2 h = __floats2half2_rn(lo, hi);
    return *reinterpret_cast<unsigned*>(&h);
}

#if defined(__has_builtin)
#if __has_builtin(__builtin_amdgcn_fdot2)
#define HAS_FDOT2 1
#endif
#endif
#ifndef HAS_FDOT2
#define HAS_FDOT2 0
#endif

__device__ __forceinline__ float fdot2u(unsigned a, unsigned b, float c) {
#if HAS_FDOT2
    return __builtin_amdgcn_fdot2(__builtin_bit_cast(f16x2, a),
                                  __builtin_bit_cast(f16x2, b), c, false);
#else
    float2 fa = unpack2(a), fb = unpack2(b);
    return fmaf(fa.y, fb.y, fmaf(fa.x, fb.x, c));
#endif
}

// ---- pass 1a: per-chunk bucket histograms (bucket-major layout) ----
__global__ __launch_bounds__(256) void hist_chunks(const int* __restrict__ dst,
                                                   int* __restrict__ hist,
                                                   int E, int nbuck, int nchunk) {
    __shared__ int cnt[512];
    for (int i = threadIdx.x; i < nbuck; i += 256) cnt[i] = 0;
    __syncthreads();
    const int base = blockIdx.x * CHUNK;
    const int lim = min(base + CHUNK, E);
    for (int e = base + threadIdx.x; e < lim; e += 256)
        atomicAdd(&cnt[dst[e] >> 8], 1);
    __syncthreads();
    for (int b = threadIdx.x; b < nbuck; b += 256)
        hist[b * nchunk + blockIdx.x] = cnt[b];
}

// ---- hierarchical exclusive prefix sum (1024 elems/block) ----
__global__ __launch_bounds__(256) void scan_blocks(const int* __restrict__ in,
                                                   int* __restrict__ pre,
                                                   int* __restrict__ bsum, int m) {
    __shared__ int lds[256];
    const int t = threadIdx.x;
    const int base = blockIdx.x * 1024 + t * 4;
    int v0 = (base + 0 < m) ? in[base + 0] : 0;
    int v1 = (base + 1 < m) ? in[base + 1] : 0;
    int v2 = (base + 2 < m) ? in[base + 2] : 0;
    int v3 = (base + 3 < m) ? in[base + 3] : 0;
    int s = v0 + v1 + v2 + v3;
    lds[t] = s;
    __syncthreads();
    for (int off = 1; off < 256; off <<= 1) {
        int add = (t >= off) ? lds[t - off] : 0;
        __syncthreads();
        lds[t] += add;
        __syncthreads();
    }
    int e = lds[t] - s;
    if (base + 0 < m) pre[base + 0] = e;
    e += v0;
    if (base + 1 < m) pre[base + 1] = e;
    e += v1;
    if (base + 2 < m) pre[base + 2] = e;
    e += v2;
    if (base + 3 < m) pre[base + 3] = e;
    if (t == 255) bsum[blockIdx.x] = lds[255];
}

__global__ __launch_bounds__(256) void scan_bsums(const int* __restrict__ bsum,
                                                  int* __restrict__ boffs, int nb) {
    __shared__ int lds[256];
    const int t = threadIdx.x;
    int v = (t < nb) ? bsum[t] : 0;
    lds[t] = v;
    __syncthreads();
    for (int off = 1; off < 256; off <<= 1) {
        int add = (t >= off) ? lds[t - off] : 0;
        __syncthreads();
        lds[t] += add;
        __syncthreads();
    }
    boffs[t] = lds[t] - v;
}

__global__ __launch_bounds__(256) void scan_add(int* __restrict__ pre,
                                                const int* __restrict__ boffs, int m) {
    for (int i = blockIdx.x * 256 + threadIdx.x; i < m; i += gridDim.x * 256)
        pre[i] += boffs[i >> 10];
}

// ---- pass 1b: partition edges into bucket-grouped runs, 4B records ----
__global__ __launch_bounds__(256) void partition(const int* __restrict__ src,
                                                 const int* __restrict__ dst,
                                                 const int* __restrict__ offs,
                                                 unsigned* __restrict__ part,
                                                 int E, int nbuck, int nchunk) {
    __shared__ int off[512];
    for (int b = threadIdx.x; b < nbuck; b += 256)
        off[b] = offs[b * nchunk + blockIdx.x];
    __syncthreads();
    const int base = blockIdx.x * CHUNK;
    const int lim = min(base + CHUNK, E);
    for (int e = base + threadIdx.x; e < lim; e += 256) {
        int d = dst[e], s = src[e];
        int pos = atomicAdd(&off[d >> 8], 1);
        part[pos] = ((unsigned)s << 8) | (unsigned)(d & 255);
    }
}

// ---- pass 2: per-bucket CSR finalize: rowptr, dinv, coalesced csr_src ----
__global__ __launch_bounds__(256) void build_bucket(const unsigned* __restrict__ part,
                                                    const int* __restrict__ offs,
                                                    int* __restrict__ csr_src,
                                                    int* __restrict__ rowptr,
                                                    float* __restrict__ dinv,
                                                    int n, int E, int nbuck, int nchunk) {
    __shared__ int cnt[256], sc[256], off[256];
    __shared__ int stage[MAXB];
    const int b = blockIdx.x;
    const int t = threadIdx.x;
    const int bstart = offs[b * nchunk];
    const int bend = (b + 1 < nbuck) ? offs[(b + 1) * nchunk] : E;
    const int bsize = bend - bstart;
    const int nodebase = b << 8;
    const int nnodes = min(256, n - nodebase);

    cnt[t] = 0;
    __syncthreads();
    for (int i = bstart + t; i < bend; i += 256)
        atomicAdd(&cnt[part[i] & 255u], 1);
    __syncthreads();
    const int deg = cnt[t];
    sc[t] = deg;
    __syncthreads();
    for (int o = 1; o < 256; o <<= 1) {
        int add = (t >= o) ? sc[t - o] : 0;
        __syncthreads();
        sc[t] += add;
        __syncthreads();
    }
    const int excl = sc[t] - deg;
    if (t < nnodes) {
        rowptr[nodebase + t] = bstart + excl;
        dinv[nodebase + t] = rsqrtf((float)(deg + 1));   // +1 self loop
    }
    if (b == 0 && t == 0) rowptr[n] = E;
    off[t] = excl;
    __syncthreads();

    if (bsize <= MAXB) {
        for (int i = bstart + t; i < bend; i += 256) {
            unsigned r = part[i];
            int pos = atomicAdd(&off[r & 255u], 1);
            stage[pos] = (int)(r >> 8);
        }
        __syncthreads();
        for (int i = t; i < bsize; i += 256)
            csr_src[bstart + i] = stage[i];
    } else {   // safety fallback
        for (int i = bstart + t; i < bend; i += 256) {
            unsigned r = part[i];
            int pos = atomicAdd(&off[r & 255u], 1);
            csr_src[bstart + pos] = (int)(r >> 8);
        }
    }
}

// hs[row] = fp16x2( dinv[row] * (x[row] @ W1) ).  2 rows/wave, dot2 inner.
// w2[k2*64+col] = (W1[2k2][col], W1[2k2+1][col]) packed half2.
__global__ __launch_bounds__(256) void gemm1(const float* __restrict__ x,
                                             const float* __restrict__ W1,
                                             const float* __restrict__ dinv,
                                             unsigned* __restrict__ hs, int n) {
    __shared__ unsigned w2[64 * HID_F];     // 16 KiB
    __shared__ unsigned xs2[4][2][64];      // per-wave 2-row stage, 2 KiB
    for (int t = threadIdx.x; t < 64 * HID_F; t += 256) {
        int k2 = t >> 6, col = t & 63;
        w2[t] = f2h2(W1[(2 * k2) * HID_F + col], W1[(2 * k2 + 1) * HID_F + col]);
    }
    __syncthreads();
    const int wave = threadIdx.x >> 6, lane = threadIdx.x & 63;
    const int npair = (n + 1) >> 1;
    for (int pr = blockIdx.x * 4 + wave; pr < npair; pr += gridDim.x * 4) {
        const int r0 = pr * 2, r1 = r0 + 1;
        const bool has1 = r1 < n;
        float2 v0 = *(const float2*)(x + (size_t)r0 * IN_F + lane * 2);
        xs2[wave][0][lane] = f2h2(v0.x, v0.y);
        if (has1) {
            float2 v1 = *(const float2*)(x + (size_t)r1 * IN_F + lane * 2);
            xs2[wave][1][lane] = f2h2(v1.x, v1.y);
        }
        float acc0 = 0.f, acc1 = 0.f;
#pragma unroll 8
        for (int k2 = 0; k2 < 64; ++k2) {
            unsigned wv = w2[k2 * 64 + lane];
            acc0 = fdot2u(xs2[wave][0][k2], wv, acc0);
            acc1 = fdot2u(xs2[wave][1][k2], wv, acc1);
        }
        acc0 *= dinv[r0];
        float o0 = __shfl_xor(acc0, 1);
        if (!(lane & 1)) hs[(size_t)r0 * 32 + (lane >> 1)] = f2h2(acc0, o0);
        if (has1) {
            acc1 *= dinv[r1];
            float o1 = __shfl_xor(acc1, 1);
            if (!(lane & 1)) hs[(size_t)r1 * 32 + (lane >> 1)] = f2h2(acc1, o1);
        }
    }
}

// One wave per node, 4 nodes/block.  Lane w of each half holds feats
// (2w, 2w+1); half 0 sums even-index edges, half 1 odd-index.
// LAYER 1: bias+relu+prescale -> fp16.  LAYER 2: plain -> fp16 (for gemm2).
template <int LAYER>
__global__ __launch_bounds__(256) void csr_agg(const int* __restrict__ rowptr,
                                               const int* __restrict__ csr_src,
                                               const float* __restrict__ dinv,
                                               const unsigned* __restrict__ hs,
                                               const float* __restrict__ b1,
                                               unsigned* __restrict__ hout, int n) {
    const int node = blockIdx.x * 4 + (threadIdx.x >> 6);
    if (node >= n) return;
    const int lane = threadIdx.x & 63;
    const int wrd  = lane & 31;
    const int half = lane >> 5;
    const int beg = rowptr[node], end = rowptr[node + 1];
    const float dn = dinv[node];

    float ax = 0.f, ay = 0.f;
    if (half == 0) {                                   // self loop, count once
        float2 s = unpack2(hs[(size_t)node * 32 + wrd]);
        ax = s.x; ay = s.y;
    }
    int p = beg;
    for (; p + 16 <= end; p += 16) {                   // 16 edges/iter, 8 per half
        int s0 = csr_src[p + half +  0];
        int s1 = csr_src[p + half +  2];
        int s2 = csr_src[p + half +  4];
        int s3 = csr_src[p + half +  6];
        int s4 = csr_src[p + half +  8];
        int s5 = csr_src[p + half + 10];
        int s6 = csr_src[p + half + 12];
        int s7 = csr_src[p + half + 14];
        unsigned u0 = hs[(size_t)s0 * 32 + wrd];
        unsigned u1 = hs[(size_t)s1 * 32 + wrd];
        unsigned u2 = hs[(size_t)s2 * 32 + wrd];
        unsigned u3 = hs[(size_t)s3 * 32 + wrd];
        unsigned u4 = hs[(size_t)s4 * 32 + wrd];
        unsigned u5 = hs[(size_t)s5 * 32 + wrd];
        unsigned u6 = hs[(size_t)s6 * 32 + wrd];
        unsigned u7 = hs[(size_t)s7 * 32 + wrd];
        float2 v0 = unpack2(u0), v1 = unpack2(u1), v2 = unpack2(u2), v3 = unpack2(u3);
        float2 v4 = unpack2(u4), v5 = unpack2(u5), v6 = unpack2(u6), v7 = unpack2(u7);
        ax += v0.x; ay += v0.y;  ax += v1.x; ay += v1.y;
        ax += v2.x; ay += v2.y;  ax += v3.x; ay += v3.y;
        ax += v4.x; ay += v4.y;  ax += v5.x; ay += v5.y;
        ax += v6.x; ay += v6.y;  ax += v7.x; ay += v7.y;
    }
    for (; p + 2 <= end; p += 2) {                     // pairs
        int s = csr_src[p + half];
        float2 v = unpack2(hs[(size_t)s * 32 + wrd]);
        ax += v.x; ay += v.y;
    }
    if (p < end && half == 0) {                        // odd remainder
        int s = csr_src[p];
        float2 v = unpack2(hs[(size_t)s * 32 + wrd]);
        ax += v.x; ay += v.y;
    }
    ax += __shfl_xor(ax, 32);                          // merge halves
    ay += __shfl_xor(ay, 32);

    if (half == 0) {
        if (LAYER == 1) {
            float2 bb = *(const float2*)(b1 + 2 * wrd);
            float vx = fmaxf(fmaf(dn, ax, bb.x), 0.f) * dn;   // relu(a1+b1), prescale
            float vy = fmaxf(fmaf(dn, ay, bb.y), 0.f) * dn;
            hout[(size_t)node * 32 + wrd] = f2h2(vx, vy);
        } else {
            hout[(size_t)node * 32 + wrd] = f2h2(dn * ax, dn * ay);
        }
    }
}

// out[n][96] = a2[n][64] @ W2[64][96] + b2.  256-row fp16 tile + dot2.
__global__ __launch_bounds__(256) void gemm2(const unsigned* __restrict__ a2h,
                                             const float* __restrict__ W2,
                                             const float* __restrict__ b2,
                                             float* __restrict__ out, int n) {
    __shared__ unsigned w2[32 * OUT_F];     // 12 KiB: (W2[2k2][j], W2[2k2+1][j])
    __shared__ float bs[OUT_F];
    __shared__ unsigned tile[256 * 32];     // 32 KiB
    for (int t = threadIdx.x; t < 32 * OUT_F; t += 256) {
        int k2 = t / OUT_F, j = t - k2 * OUT_F;
        w2[t] = f2h2(W2[(2 * k2) * OUT_F + j], W2[(2 * k2 + 1) * OUT_F + j]);
    }
    for (int t = threadIdx.x; t < OUT_F; t += 256) bs[t] = b2[t];
    const int base = blockIdx.x * 256;
    const int rows = min(256, n - base);
    const uint4* srcv = (const uint4*)(a2h + (size_t)base * 32);
    const int nvec = rows * 8;              // rows*32/4
    for (int t = threadIdx.x; t < nvec; t += 256)
        ((uint4*)tile)[t] = srcv[t];
    __syncthreads();
    const int total = rows * OUT_F;
    for (int idx = threadIdx.x; idx < total; idx += 256) {
        int r = idx / OUT_F, j = idx - r * OUT_F;
        float acc = bs[j];
#pragma unroll
        for (int k2 = 0; k2 < 32; ++k2)
            acc = fdot2u(tile[r * 32 + k2], w2[k2 * OUT_F + j], acc);
        out[(size_t)(base + r) * OUT_F + j] = acc;
    }
}

extern "C" void kernel_launch(void* const* d_in, const int* in_sizes, int n_in,
                              void* d_out, int out_size, void* d_ws, size_t ws_size,
                              hipStream_t stream) {
    const float* x  = (const float*)d_in[0];
    const int*   ei = (const int*)d_in[1];
    const float* W1 = (const float*)d_in[2];
    const float* b1 = (const float*)d_in[3];
    const float* W2 = (const float*)d_in[4];
    const float* b2 = (const float*)d_in[5];
    float* out = (float*)d_out;

    const int n = in_sizes[0] / IN_F;          // 100000
    const int E = in_sizes[1] / 2;             // 1600000
    const int* src = ei;
    const int* dst = ei + E;
    const int nbuck  = (n + 255) >> 8;         // 391
    const int nchunk = (E + CHUNK - 1) / CHUNK;// 391
    const int M = nbuck * nchunk;              // 152881
    const int NBS = (M + 1023) / 1024;
    const int nquad = (n + 3) / 4;             // 25000
    const int ntile = (n + 255) / 256;         // 391

    char* ws = (char*)d_ws;
    size_t off = 0;
    auto alloc = [&](size_t bytes) { void* p = ws + off; off = (off + bytes + 255) & ~(size_t)255; return p; };
    int*      hist    = (int*)alloc((size_t)M * 4);
    int*      offs    = (int*)alloc((size_t)M * 4);
    int*      bsum    = (int*)alloc(256 * 4);
    int*      boffs   = (int*)alloc(256 * 4);
    unsigned* part    = (unsigned*)alloc((size_t)E * 4);
    int*      csr_src = (int*)alloc((size_t)E * 4);
    int*      rowptr  = (int*)alloc((size_t)(n + 1) * 4);
    float*    dinv    = (float*)alloc((size_t)n * 4);
    unsigned* hs      = (unsigned*)alloc((size_t)n * 32 * 4);
    unsigned* hs2     = (unsigned*)alloc((size_t)n * 32 * 4);
    unsigned* a2h     = (unsigned*)alloc((size_t)n * 32 * 4);

    // CSR build: histogram -> scan -> partition -> per-bucket finalize
    hist_chunks <<<nchunk, 256, 0, stream>>>(dst, hist, E, nbuck, nchunk);
    scan_blocks <<<NBS, 256, 0, stream>>>(hist, offs, bsum, M);
    scan_bsums  <<<1, 256, 0, stream>>>(bsum, boffs, NBS);
    scan_add    <<<512, 256, 0, stream>>>(offs, boffs, M);
    partition   <<<nchunk, 256, 0, stream>>>(src, dst, offs, part, E, nbuck, nchunk);
    build_bucket<<<nbuck, 256, 0, stream>>>(part, offs, csr_src, rowptr, dinv,
                                            n, E, nbuck, nchunk);

    // network
    gemm1      <<<2048, 256, 0, stream>>>(x, W1, dinv, hs, n);
    csr_agg<1> <<<nquad, 256, 0, stream>>>(rowptr, csr_src, dinv, hs, b1, hs2, n);
    csr_agg<2> <<<nquad, 256, 0, stream>>>(rowptr, csr_src, dinv, hs2, NULL, a2h, n);
    gemm2      <<<ntile, 256, 0, stream>>>(a2h, W2, b2, out, n);
}

// Round 8
// 205.717 us; speedup vs baseline: 2.3250x; 1.2154x over previous
//
#include <hip/hip_runtime.h>
#include <hip/hip_fp16.h>

// ConformalGCN: 2-layer GCN, N=100000, E=1600000 (+self loops).
// R7: csr_agg restructured to quarter-wave row groups (uint2 gathers, 4 edges
//     per load instruction, half the VMEM/addr instructions); gemm2 register-
//     tiled 4 outputs/thread (LDS ops per dot2: 2 -> 0.5); scan_add folded
//     into partition/build_bucket. CSR radix build (R5) + gemm1 (R6) kept.

#define IN_F  128
#define HID_F 64
#define OUT_F 96
#define CHUNK 4096
#define MAXB  8192

typedef _Float16 f16x2 __attribute__((ext_vector_type(2)));

__device__ __forceinline__ float2 unpack2(unsigned u) {
    __half2 h = *reinterpret_cast<__half2*>(&u);
    return __half22float2(h);
}
__device__ __forceinline__ unsigned f2h2(float lo, float hi) {
    __half2 h = __floats2half2_rn(lo, hi);
    return *reinterpret_cast<unsigned*>(&h);
}

#if defined(__has_builtin)
#if __has_builtin(__builtin_amdgcn_fdot2)
#define HAS_FDOT2 1
#endif
#endif
#ifndef HAS_FDOT2
#define HAS_FDOT2 0
#endif

__device__ __forceinline__ float fdot2u(unsigned a, unsigned b, float c) {
#if HAS_FDOT2
    return __builtin_amdgcn_fdot2(__builtin_bit_cast(f16x2, a),
                                  __builtin_bit_cast(f16x2, b), c, false);
#else
    float2 fa = unpack2(a), fb = unpack2(b);
    return fmaf(fa.y, fb.y, fmaf(fa.x, fb.x, c));
#endif
}

// ---- pass 1a: per-chunk bucket histograms (bucket-major layout) ----
__global__ __launch_bounds__(256) void hist_chunks(const int* __restrict__ dst,
                                                   int* __restrict__ hist,
                                                   int E, int nbuck, int nchunk) {
    __shared__ int cnt[512];
    for (int i = threadIdx.x; i < nbuck; i += 256) cnt[i] = 0;
    __syncthreads();
    const int base = blockIdx.x * CHUNK;
    const int lim = min(base + CHUNK, E);
    for (int e = base + threadIdx.x; e < lim; e += 256)
        atomicAdd(&cnt[dst[e] >> 8], 1);
    __syncthreads();
    for (int b = threadIdx.x; b < nbuck; b += 256)
        hist[b * nchunk + blockIdx.x] = cnt[b];
}

// ---- hierarchical exclusive prefix sum (1024 elems/block) ----
__global__ __launch_bounds__(256) void scan_blocks(const int* __restrict__ in,
                                                   int* __restrict__ pre,
                                                   int* __restrict__ bsum, int m) {
    __shared__ int lds[256];
    const int t = threadIdx.x;
    const int base = blockIdx.x * 1024 + t * 4;
    int v0 = (base + 0 < m) ? in[base + 0] : 0;
    int v1 = (base + 1 < m) ? in[base + 1] : 0;
    int v2 = (base + 2 < m) ? in[base + 2] : 0;
    int v3 = (base + 3 < m) ? in[base + 3] : 0;
    int s = v0 + v1 + v2 + v3;
    lds[t] = s;
    __syncthreads();
    for (int off = 1; off < 256; off <<= 1) {
        int add = (t >= off) ? lds[t - off] : 0;
        __syncthreads();
        lds[t] += add;
        __syncthreads();
    }
    int e = lds[t] - s;
    if (base + 0 < m) pre[base + 0] = e;
    e += v0;
    if (base + 1 < m) pre[base + 1] = e;
    e += v1;
    if (base + 2 < m) pre[base + 2] = e;
    e += v2;
    if (base + 3 < m) pre[base + 3] = e;
    if (t == 255) bsum[blockIdx.x] = lds[255];
}

__global__ __launch_bounds__(256) void scan_bsums(const int* __restrict__ bsum,
                                                  int* __restrict__ boffs, int nb) {
    __shared__ int lds[256];
    const int t = threadIdx.x;
    int v = (t < nb) ? bsum[t] : 0;
    lds[t] = v;
    __syncthreads();
    for (int off = 1; off < 256; off <<= 1) {
        int add = (t >= off) ? lds[t - off] : 0;
        __syncthreads();
        lds[t] += add;
        __syncthreads();
    }
    boffs[t] = lds[t] - v;
}

// ---- pass 1b: partition edges into bucket-grouped runs, 4B records ----
// offs is the per-1024-block scan; boffs folded in at read (scan_add removed).
__global__ __launch_bounds__(256) void partition(const int* __restrict__ src,
                                                 const int* __restrict__ dst,
                                                 const int* __restrict__ offs,
                                                 const int* __restrict__ boffs,
                                                 unsigned* __restrict__ part,
                                                 int E, int nbuck, int nchunk) {
    __shared__ int off[512];
    for (int b = threadIdx.x; b < nbuck; b += 256) {
        int idx = b * nchunk + blockIdx.x;
        off[b] = offs[idx] + boffs[idx >> 10];
    }
    __syncthreads();
    const int base = blockIdx.x * CHUNK;
    const int lim = min(base + CHUNK, E);
    for (int e = base + threadIdx.x; e < lim; e += 256) {
        int d = dst[e], s = src[e];
        int pos = atomicAdd(&off[d >> 8], 1);
        part[pos] = ((unsigned)s << 8) | (unsigned)(d & 255);
    }
}

// ---- pass 2: per-bucket CSR finalize: rowptr, dinv, coalesced csr_src ----
__global__ __launch_bounds__(256) void build_bucket(const unsigned* __restrict__ part,
                                                    const int* __restrict__ offs,
                                                    const int* __restrict__ boffs,
                                                    int* __restrict__ csr_src,
                                                    int* __restrict__ rowptr,
                                                    float* __restrict__ dinv,
                                                    int n, int E, int nbuck, int nchunk) {
    __shared__ int cnt[256], sc[256], off[256];
    __shared__ int stage[MAXB];
    const int b = blockIdx.x;
    const int t = threadIdx.x;
    const int i0 = b * nchunk;
    const int bstart = offs[i0] + boffs[i0 >> 10];
    int bend = E;
    if (b + 1 < nbuck) {
        const int i1 = (b + 1) * nchunk;
        bend = offs[i1] + boffs[i1 >> 10];
    }
    const int bsize = bend - bstart;
    const int nodebase = b << 8;
    const int nnodes = min(256, n - nodebase);

    cnt[t] = 0;
    __syncthreads();
    for (int i = bstart + t; i < bend; i += 256)
        atomicAdd(&cnt[part[i] & 255u], 1);
    __syncthreads();
    const int deg = cnt[t];
    sc[t] = deg;
    __syncthreads();
    for (int o = 1; o < 256; o <<= 1) {
        int add = (t >= o) ? sc[t - o] : 0;
        __syncthreads();
        sc[t] += add;
        __syncthreads();
    }
    const int excl = sc[t] - deg;
    if (t < nnodes) {
        rowptr[nodebase + t] = bstart + excl;
        dinv[nodebase + t] = rsqrtf((float)(deg + 1));   // +1 self loop
    }
    if (b == 0 && t == 0) rowptr[n] = E;
    off[t] = excl;
    __syncthreads();

    if (bsize <= MAXB) {
        for (int i = bstart + t; i < bend; i += 256) {
            unsigned r = part[i];
            int pos = atomicAdd(&off[r & 255u], 1);
            stage[pos] = (int)(r >> 8);
        }
        __syncthreads();
        for (int i = t; i < bsize; i += 256)
            csr_src[bstart + i] = stage[i];
    } else {   // safety fallback
        for (int i = bstart + t; i < bend; i += 256) {
            unsigned r = part[i];
            int pos = atomicAdd(&off[r & 255u], 1);
            csr_src[bstart + pos] = (int)(r >> 8);
        }
    }
}

// hs[row] = fp16x2( dinv[row] * (x[row] @ W1) ).  2 rows/wave, dot2 inner.
__global__ __launch_bounds__(256) void gemm1(const float* __restrict__ x,
                                             const float* __restrict__ W1,
                                             const float* __restrict__ dinv,
                                             unsigned* __restrict__ hs, int n) {
    __shared__ unsigned w2[64 * HID_F];     // 16 KiB
    __shared__ unsigned xs2[4][2][64];
    for (int t = threadIdx.x; t < 64 * HID_F; t += 256) {
        int k2 = t >> 6, col = t & 63;
        w2[t] = f2h2(W1[(2 * k2) * HID_F + col], W1[(2 * k2 + 1) * HID_F + col]);
    }
    __syncthreads();
    const int wave = threadIdx.x >> 6, lane = threadIdx.x & 63;
    const int npair = (n + 1) >> 1;
    for (int pr = blockIdx.x * 4 + wave; pr < npair; pr += gridDim.x * 4) {
        const int r0 = pr * 2, r1 = r0 + 1;
        const bool has1 = r1 < n;
        float2 v0 = *(const float2*)(x + (size_t)r0 * IN_F + lane * 2);
        xs2[wave][0][lane] = f2h2(v0.x, v0.y);
        if (has1) {
            float2 v1 = *(const float2*)(x + (size_t)r1 * IN_F + lane * 2);
            xs2[wave][1][lane] = f2h2(v1.x, v1.y);
        }
        float acc0 = 0.f, acc1 = 0.f;
#pragma unroll 8
        for (int k2 = 0; k2 < 64; ++k2) {
            unsigned wv = w2[k2 * 64 + lane];
            acc0 = fdot2u(xs2[wave][0][k2], wv, acc0);
            acc1 = fdot2u(xs2[wave][1][k2], wv, acc1);
        }
        acc0 *= dinv[r0];
        float o0 = __shfl_xor(acc0, 1);
        if (!(lane & 1)) hs[(size_t)r0 * 32 + (lane >> 1)] = f2h2(acc0, o0);
        if (has1) {
            acc1 *= dinv[r1];
            float o1 = __shfl_xor(acc1, 1);
            if (!(lane & 1)) hs[(size_t)r1 * 32 + (lane >> 1)] = f2h2(acc1, o1);
        }
    }
}

// One wave per node, 4 nodes/block.  Quarter-wave row groups: slot g=lane>>4
// owns edge p+off+g; lane w=lane&15 holds feats 4w..4w+3 via uint2.
// One idx load instr = 4 edges; one gather instr = 4 full 128B rows.
// Epilogue: shfl_xor(16/32) reduce; lanes 0-15 store the row.
template <int LAYER>
__global__ __launch_bounds__(256) void csr_agg(const int* __restrict__ rowptr,
                                               const int* __restrict__ csr_src,
                                               const float* __restrict__ dinv,
                                               const unsigned* __restrict__ hs,
                                               const float* __restrict__ bias,
                                               unsigned* __restrict__ hout, int n) {
    const int node = blockIdx.x * 4 + (threadIdx.x >> 6);
    if (node >= n) return;
    const int lane = threadIdx.x & 63;
    const int g = lane >> 4;          // edge slot 0..3
    const int w = lane & 15;          // feats 4w..4w+3
    const int beg = rowptr[node], end = rowptr[node + 1];
    const float dn = dinv[node];
    const unsigned* __restrict__ hw = hs + 2 * w;

    float a0 = 0.f, a1 = 0.f, a2 = 0.f, a3 = 0.f;
    float c0 = 0.f, c1 = 0.f, c2 = 0.f, c3 = 0.f;
    if (g == 0) {                                      // self loop, once
        uint2 su = *(const uint2*)(hw + (size_t)node * 32);
        float2 s0 = unpack2(su.x), s1 = unpack2(su.y);
        a0 = s0.x; a1 = s0.y; a2 = s1.x; a3 = s1.y;
    }
    int p = beg;
    for (; p + 16 <= end; p += 16) {                   // 16 edges/iter
        int i0 = csr_src[p + g];
        int i1 = csr_src[p + 4 + g];
        int i2 = csr_src[p + 8 + g];
        int i3 = csr_src[p + 12 + g];
        uint2 u0 = *(const uint2*)(hw + (size_t)i0 * 32);
        uint2 u1 = *(const uint2*)(hw + (size_t)i1 * 32);
        uint2 u2 = *(const uint2*)(hw + (size_t)i2 * 32);
        uint2 u3 = *(const uint2*)(hw + (size_t)i3 * 32);
        float2 f;
        f = unpack2(u0.x); a0 += f.x; a1 += f.y;
        f = unpack2(u0.y); a2 += f.x; a3 += f.y;
        f = unpack2(u1.x); c0 += f.x; c1 += f.y;
        f = unpack2(u1.y); c2 += f.x; c3 += f.y;
        f = unpack2(u2.x); a0 += f.x; a1 += f.y;
        f = unpack2(u2.y); a2 += f.x; a3 += f.y;
        f = unpack2(u3.x); c0 += f.x; c1 += f.y;
        f = unpack2(u3.y); c2 += f.x; c3 += f.y;
    }
    for (; p < end; p += 4) {                          // remainder, 4 at a time
        if (p + g < end) {
            int i = csr_src[p + g];
            uint2 u = *(const uint2*)(hw + (size_t)i * 32);
            float2 f = unpack2(u.x); a0 += f.x; a1 += f.y;
            f = unpack2(u.y); a2 += f.x; a3 += f.y;
        }
    }
    a0 += c0; a1 += c1; a2 += c2; a3 += c3;
    a0 += __shfl_xor(a0, 16); a0 += __shfl_xor(a0, 32);
    a1 += __shfl_xor(a1, 16); a1 += __shfl_xor(a1, 32);
    a2 += __shfl_xor(a2, 16); a2 += __shfl_xor(a2, 32);
    a3 += __shfl_xor(a3, 16); a3 += __shfl_xor(a3, 32);

    if (g == 0) {
        float o0, o1, o2, o3;
        if (LAYER == 1) {
            float4 bb = *(const float4*)(bias + 4 * w);
            o0 = fmaxf(fmaf(dn, a0, bb.x), 0.f) * dn;   // relu(a1+b1), prescale
            o1 = fmaxf(fmaf(dn, a1, bb.y), 0.f) * dn;
            o2 = fmaxf(fmaf(dn, a2, bb.z), 0.f) * dn;
            o3 = fmaxf(fmaf(dn, a3, bb.w), 0.f) * dn;
        } else {
            o0 = dn * a0; o1 = dn * a1; o2 = dn * a2; o3 = dn * a3;
        }
        uint2 ov;
        ov.x = f2h2(o0, o1);
        ov.y = f2h2(o2, o3);
        *(uint2*)(hout + (size_t)node * 32 + 2 * w) = ov;
    }
}

// out[n][96] = a2[n][64] @ W2[64][96] + b2.  fp16 tile (+1 pad) in LDS,
// 4 outputs/thread: per k2 = 1 ds_read_b32 (tile) + 1 ds_read_b128 (w2).
__global__ __launch_bounds__(256) void gemm2(const unsigned* __restrict__ a2h,
                                             const float* __restrict__ W2,
                                             const float* __restrict__ b2,
                                             float* __restrict__ out, int n) {
    __shared__ unsigned w2[32 * OUT_F];     // [k2][j], 12 KiB
    __shared__ float bs[OUT_F];
    __shared__ unsigned tile[256 * 33];     // +1 word pad per row, 33.8 KiB
    for (int t = threadIdx.x; t < 32 * OUT_F; t += 256) {
        int k2 = t / OUT_F, j = t - k2 * OUT_F;
        w2[t] = f2h2(W2[(2 * k2) * OUT_F + j], W2[(2 * k2 + 1) * OUT_F + j]);
    }
    for (int t = threadIdx.x; t < OUT_F; t += 256) bs[t] = b2[t];
    const int base = blockIdx.x * 256;
    const int rows = min(256, n - base);
    const uint4* srcv = (const uint4*)(a2h + (size_t)base * 32);
    const int nvec = rows * 8;              // uint4s
    for (int t = threadIdx.x; t < nvec; t += 256) {
        uint4 v = srcv[t];
        int r = t >> 3, w0 = (t & 7) * 4;
        unsigned* d = &tile[r * 33 + w0];
        d[0] = v.x; d[1] = v.y; d[2] = v.z; d[3] = v.w;
    }
    __syncthreads();
    const int total = rows * 24;            // (row, j-quad)
    for (int idx = threadIdx.x; idx < total; idx += 256) {
        int r = idx / 24, jq = idx - r * 24, j = jq * 4;
        float4 bb = *(const float4*)&bs[j];
        float acc0 = bb.x, acc1 = bb.y, acc2 = bb.z, acc3 = bb.w;
        const unsigned* tr = &tile[r * 33];
#pragma unroll
        for (int k2 = 0; k2 < 32; ++k2) {
            unsigned tv = tr[k2];
            uint4 wv = *(const uint4*)&w2[k2 * OUT_F + j];
            acc0 = fdot2u(tv, wv.x, acc0);
            acc1 = fdot2u(tv, wv.y, acc1);
            acc2 = fdot2u(tv, wv.z, acc2);
            acc3 = fdot2u(tv, wv.w, acc3);
        }
        *(float4*)(out + (size_t)(base + r) * OUT_F + j) =
            make_float4(acc0, acc1, acc2, acc3);
    }
}

extern "C" void kernel_launch(void* const* d_in, const int* in_sizes, int n_in,
                              void* d_out, int out_size, void* d_ws, size_t ws_size,
                              hipStream_t stream) {
    const float* x  = (const float*)d_in[0];
    const int*   ei = (const int*)d_in[1];
    const float* W1 = (const float*)d_in[2];
    const float* b1 = (const float*)d_in[3];
    const float* W2 = (const float*)d_in[4];
    const float* b2 = (const float*)d_in[5];
    float* out = (float*)d_out;

    const int n = in_sizes[0] / IN_F;          // 100000
    const int E = in_sizes[1] / 2;             // 1600000
    const int* src = ei;
    const int* dst = ei + E;
    const int nbuck  = (n + 255) >> 8;         // 391
    const int nchunk = (E + CHUNK - 1) / CHUNK;// 391
    const int M = nbuck * nchunk;              // 152881
    const int NBS = (M + 1023) / 1024;
    const int nquad = (n + 3) / 4;             // 25000
    const int ntile = (n + 255) / 256;         // 391

    char* ws = (char*)d_ws;
    size_t off = 0;
    auto alloc = [&](size_t bytes) { void* p = ws + off; off = (off + bytes + 255) & ~(size_t)255; return p; };
    int*      hist    = (int*)alloc((size_t)M * 4);
    int*      offs    = (int*)alloc((size_t)M * 4);
    int*      bsum    = (int*)alloc(256 * 4);
    int*      boffs   = (int*)alloc(256 * 4);
    unsigned* part    = (unsigned*)alloc((size_t)E * 4);
    int*      csr_src = (int*)alloc((size_t)E * 4);
    int*      rowptr  = (int*)alloc((size_t)(n + 1) * 4);
    float*    dinv    = (float*)alloc((size_t)n * 4);
    unsigned* hs      = (unsigned*)alloc((size_t)n * 32 * 4);
    unsigned* hs2     = (unsigned*)alloc((size_t)n * 32 * 4);
    unsigned* a2h     = (unsigned*)alloc((size_t)n * 32 * 4);

    // CSR build: histogram -> scan -> partition -> per-bucket finalize
    hist_chunks <<<nchunk, 256, 0, stream>>>(dst, hist, E, nbuck, nchunk);
    scan_blocks <<<NBS, 256, 0, stream>>>(hist, offs, bsum, M);
    scan_bsums  <<<1, 256, 0, stream>>>(bsum, boffs, NBS);
    partition   <<<nchunk, 256, 0, stream>>>(src, dst, offs, boffs, part, E, nbuck, nchunk);
    build_bucket<<<nbuck, 256, 0, stream>>>(part, offs, boffs, csr_src, rowptr, dinv,
                                            n, E, nbuck, nchunk);

    // network
    gemm1      <<<2048, 256, 0, stream>>>(x, W1, dinv, hs, n);
    csr_agg<1> <<<nquad, 256, 0, stream>>>(rowptr, csr_src, dinv, hs, b1, hs2, n);
    csr_agg<2> <<<nquad, 256, 0, stream>>>(rowptr, csr_src, dinv, hs2, NULL, a2h, n);
    gemm2      <<<ntile, 256, 0, stream>>>(a2h, W2, b2, out, n);
}

// Round 9
// 196.670 us; speedup vs baseline: 2.4320x; 1.0460x over previous
//
#include <hip/hip_runtime.h>
#include <hip/hip_fp16.h>

// ConformalGCN: 2-layer GCN, N=100000, E=1600000 (+self loops).
// R8: padded CSR (rows %4, sentinel src=n with zero feature row) ->
//     int4 index loads + unmasked tail; nodetab int4 (beg,end,dinv) single
//     setup load; grid-stride csr_agg w/ next-node prefetch; gemm1 staged
//     rows packed uint2 (2 LDS reads/k2). Radix CSR build otherwise R7.

#define IN_F  128
#define HID_F 64
#define OUT_F 96
#define CHUNK 4096
#define MAXB  9216          // stage capacity (padded bucket size), 36 KiB
#define AGG_BLOCKS 4096

typedef _Float16 f16x2 __attribute__((ext_vector_type(2)));

__device__ __forceinline__ float2 unpack2(unsigned u) {
    __half2 h = *reinterpret_cast<__half2*>(&u);
    return __half22float2(h);
}
__device__ __forceinline__ unsigned f2h2(float lo, float hi) {
    __half2 h = __floats2half2_rn(lo, hi);
    return *reinterpret_cast<unsigned*>(&h);
}

#if defined(__has_builtin)
#if __has_builtin(__builtin_amdgcn_fdot2)
#define HAS_FDOT2 1
#endif
#endif
#ifndef HAS_FDOT2
#define HAS_FDOT2 0
#endif

__device__ __forceinline__ float fdot2u(unsigned a, unsigned b, float c) {
#if HAS_FDOT2
    return __builtin_amdgcn_fdot2(__builtin_bit_cast(f16x2, a),
                                  __builtin_bit_cast(f16x2, b), c, false);
#else
    float2 fa = unpack2(a), fb = unpack2(b);
    return fmaf(fa.y, fb.y, fmaf(fa.x, fb.x, c));
#endif
}

// zero the sentinel feature rows hs[n], hs2[n]
__global__ __launch_bounds__(64) void init_sentinel(unsigned* __restrict__ hs,
                                                    unsigned* __restrict__ hs2, int n) {
    int t = threadIdx.x;
    if (t < 32) {
        hs[(size_t)n * 32 + t] = 0u;
        hs2[(size_t)n * 32 + t] = 0u;
    }
}

// ---- pass 1a: per-chunk bucket histograms (bucket-major layout) ----
__global__ __launch_bounds__(256) void hist_chunks(const int* __restrict__ dst,
                                                   int* __restrict__ hist,
                                                   int E, int nbuck, int nchunk) {
    __shared__ int cnt[512];
    for (int i = threadIdx.x; i < nbuck; i += 256) cnt[i] = 0;
    __syncthreads();
    const int base = blockIdx.x * CHUNK;
    const int lim = min(base + CHUNK, E);
    for (int e = base + threadIdx.x; e < lim; e += 256)
        atomicAdd(&cnt[dst[e] >> 8], 1);
    __syncthreads();
    for (int b = threadIdx.x; b < nbuck; b += 256)
        hist[b * nchunk + blockIdx.x] = cnt[b];
}

// ---- hierarchical exclusive prefix sum (1024 elems/block) ----
__global__ __launch_bounds__(256) void scan_blocks(const int* __restrict__ in,
                                                   int* __restrict__ pre,
                                                   int* __restrict__ bsum, int m) {
    __shared__ int lds[256];
    const int t = threadIdx.x;
    const int base = blockIdx.x * 1024 + t * 4;
    int v0 = (base + 0 < m) ? in[base + 0] : 0;
    int v1 = (base + 1 < m) ? in[base + 1] : 0;
    int v2 = (base + 2 < m) ? in[base + 2] : 0;
    int v3 = (base + 3 < m) ? in[base + 3] : 0;
    int s = v0 + v1 + v2 + v3;
    lds[t] = s;
    __syncthreads();
    for (int off = 1; off < 256; off <<= 1) {
        int add = (t >= off) ? lds[t - off] : 0;
        __syncthreads();
        lds[t] += add;
        __syncthreads();
    }
    int e = lds[t] - s;
    if (base + 0 < m) pre[base + 0] = e;
    e += v0;
    if (base + 1 < m) pre[base + 1] = e;
    e += v1;
    if (base + 2 < m) pre[base + 2] = e;
    e += v2;
    if (base + 3 < m) pre[base + 3] = e;
    if (t == 255) bsum[blockIdx.x] = lds[255];
}

__global__ __launch_bounds__(256) void scan_bsums(const int* __restrict__ bsum,
                                                  int* __restrict__ boffs, int nb) {
    __shared__ int lds[256];
    const int t = threadIdx.x;
    int v = (t < nb) ? bsum[t] : 0;
    lds[t] = v;
    __syncthreads();
    for (int off = 1; off < 256; off <<= 1) {
        int add = (t >= off) ? lds[t - off] : 0;
        __syncthreads();
        lds[t] += add;
        __syncthreads();
    }
    boffs[t] = lds[t] - v;
}

// ---- pass 1b: partition edges into bucket-grouped runs, 4B records ----
__global__ __launch_bounds__(256) void partition(const int* __restrict__ src,
                                                 const int* __restrict__ dst,
                                                 const int* __restrict__ offs,
                                                 const int* __restrict__ boffs,
                                                 unsigned* __restrict__ part,
                                                 int E, int nbuck, int nchunk) {
    __shared__ int off[512];
    for (int b = threadIdx.x; b < nbuck; b += 256) {
        int idx = b * nchunk + blockIdx.x;
        off[b] = offs[idx] + boffs[idx >> 10];
    }
    __syncthreads();
    const int base = blockIdx.x * CHUNK;
    const int lim = min(base + CHUNK, E);
    for (int e = base + threadIdx.x; e < lim; e += 256) {
        int d = dst[e], s = src[e];
        int pos = atomicAdd(&off[d >> 8], 1);
        part[pos] = ((unsigned)s << 8) | (unsigned)(d & 255);
    }
}

// ---- pass 2: per-bucket padded CSR finalize ----
// Padded row length = (deg+3)&~3, pad slots = sentinel src n (zero row).
// Bucket b's padded region starts at bstart + b*1024 (max pad 256*3 < 1024).
// Emits nodetab[node] = {beg, end_padded, dinv_bits, 0} and dinv[].
__global__ __launch_bounds__(256) void build_bucket(const unsigned* __restrict__ part,
                                                    const int* __restrict__ offs,
                                                    const int* __restrict__ boffs,
                                                    int* __restrict__ csr_src,
                                                    int4* __restrict__ nodetab,
                                                    float* __restrict__ dinv,
                                                    int n, int E, int nbuck, int nchunk) {
    __shared__ int cnt[256], sc[256], off[256];
    __shared__ int stage[MAXB];
    const int b = blockIdx.x;
    const int t = threadIdx.x;
    const int i0 = b * nchunk;
    const int bstart = offs[i0] + boffs[i0 >> 10];
    int bend = E;
    if (b + 1 < nbuck) {
        const int i1 = (b + 1) * nchunk;
        bend = offs[i1] + boffs[i1 >> 10];
    }
    const int bstart_pad = bstart + b * 1024;
    const int nodebase = b << 8;
    const int nnodes = min(256, n - nodebase);

    cnt[t] = 0;
    __syncthreads();
    for (int i = bstart + t; i < bend; i += 256)
        atomicAdd(&cnt[part[i] & 255u], 1);
    __syncthreads();
    const int deg = cnt[t];
    const int pdeg = (deg + 3) & ~3;
    sc[t] = pdeg;
    __syncthreads();
    for (int o = 1; o < 256; o <<= 1) {
        int add = (t >= o) ? sc[t - o] : 0;
        __syncthreads();
        sc[t] += add;
        __syncthreads();
    }
    const int pexcl = sc[t] - pdeg;
    const int psize = sc[255];
    if (t < nnodes) {
        float dv = rsqrtf((float)(deg + 1));   // +1 self loop
        nodetab[nodebase + t] = make_int4(bstart_pad + pexcl,
                                          bstart_pad + pexcl + pdeg,
                                          __float_as_int(dv), 0);
        dinv[nodebase + t] = dv;
    }
    off[t] = pexcl;
    __syncthreads();

    if (psize <= MAXB) {
        for (int i = t; i < psize; i += 256) stage[i] = n;   // sentinel fill
        __syncthreads();
        for (int i = bstart + t; i < bend; i += 256) {
            unsigned r = part[i];
            int pos = atomicAdd(&off[r & 255u], 1);
            stage[pos] = (int)(r >> 8);
        }
        __syncthreads();
        for (int i = t; i < psize; i += 256)
            csr_src[bstart_pad + i] = stage[i];
    } else {   // safety fallback
        for (int i = t; i < psize; i += 256) csr_src[bstart_pad + i] = n;
        __syncthreads();
        for (int i = bstart + t; i < bend; i += 256) {
            unsigned r = part[i];
            int pos = atomicAdd(&off[r & 255u], 1);
            csr_src[bstart_pad + pos] = (int)(r >> 8);
        }
    }
}

// hs[row] = fp16x2( dinv[row] * (x[row] @ W1) ).  2 rows/wave, dot2 inner,
// staged rows packed as uint2 -> 2 LDS reads per k2.
__global__ __launch_bounds__(256) void gemm1(const float* __restrict__ x,
                                             const float* __restrict__ W1,
                                             const float* __restrict__ dinv,
                                             unsigned* __restrict__ hs, int n) {
    __shared__ unsigned w2[64 * HID_F];     // 16 KiB
    __shared__ uint2 xs2p[4][64];           // 2 KiB
    for (int t = threadIdx.x; t < 64 * HID_F; t += 256) {
        int k2 = t >> 6, col = t & 63;
        w2[t] = f2h2(W1[(2 * k2) * HID_F + col], W1[(2 * k2 + 1) * HID_F + col]);
    }
    __syncthreads();
    const int wave = threadIdx.x >> 6, lane = threadIdx.x & 63;
    const int npair = (n + 1) >> 1;
    for (int pr = blockIdx.x * 4 + wave; pr < npair; pr += gridDim.x * 4) {
        const int r0 = pr * 2, r1 = r0 + 1;
        const bool has1 = r1 < n;
        float2 v0 = *(const float2*)(x + (size_t)r0 * IN_F + lane * 2);
        float2 v1 = make_float2(0.f, 0.f);
        if (has1) v1 = *(const float2*)(x + (size_t)r1 * IN_F + lane * 2);
        xs2p[wave][lane] = make_uint2(f2h2(v0.x, v0.y), f2h2(v1.x, v1.y));
        float acc0 = 0.f, acc1 = 0.f;
#pragma unroll 8
        for (int k2 = 0; k2 < 64; ++k2) {
            uint2 xv = xs2p[wave][k2];
            unsigned wv = w2[k2 * 64 + lane];
            acc0 = fdot2u(xv.x, wv, acc0);
            acc1 = fdot2u(xv.y, wv, acc1);
        }
        acc0 *= dinv[r0];
        float o0 = __shfl_xor(acc0, 1);
        if (!(lane & 1)) hs[(size_t)r0 * 32 + (lane >> 1)] = f2h2(acc0, o0);
        if (has1) {
            acc1 *= dinv[r1];
            float o1 = __shfl_xor(acc1, 1);
            if (!(lane & 1)) hs[(size_t)r1 * 32 + (lane >> 1)] = f2h2(acc1, o1);
        }
    }
}

// Grid-stride, one wave per node.  Quarter-wave slots: slot g=lane>>4 owns
// edges 4g..4g+3 of each 16-block via one int4 idx load; lane w=lane&15
// holds feats 4w..4w+3 (uint2 gather).  Padded rows: no masking anywhere.
template <int LAYER>
__global__ __launch_bounds__(256) void csr_agg(const int4* __restrict__ nodetab,
                                               const int* __restrict__ csr_src,
                                               const unsigned* __restrict__ hs,
                                               const float* __restrict__ bias,
                                               unsigned* __restrict__ hout, int n) {
    const int lane = threadIdx.x & 63;
    const int g = lane >> 4;          // edge slot 0..3
    const int w = lane & 15;          // feats 4w..4w+3
    const unsigned* __restrict__ hw = hs + 2 * w;
    const int STR = gridDim.x * 4;

    int node = blockIdx.x * 4 + (threadIdx.x >> 6);
    if (node >= n) return;
    int4 nt = nodetab[node];
    for (;;) {
        const int nxt = node + STR;
        const bool more = nxt < n;
        int4 ntn;
        if (more) ntn = nodetab[nxt];          // prefetch next node's record

        int p = nt.x;
        const int end = nt.y;
        const float dn = __int_as_float(nt.z);
        float a0 = 0.f, a1 = 0.f, a2 = 0.f, a3 = 0.f;
        float c0 = 0.f, c1 = 0.f, c2 = 0.f, c3 = 0.f;
        if (g == 0) {                                      // self loop, once
            uint2 su = *(const uint2*)(hw + (size_t)node * 32);
            float2 s0 = unpack2(su.x), s1 = unpack2(su.y);
            a0 = s0.x; a1 = s0.y; a2 = s1.x; a3 = s1.y;
        }
        for (; p + 16 <= end; p += 16) {                   // 16 edges/iter
            int4 iv = *(const int4*)&csr_src[p + 4 * g];   // 4 idx, one load
            uint2 u0 = *(const uint2*)(hw + (size_t)iv.x * 32);
            uint2 u1 = *(const uint2*)(hw + (size_t)iv.y * 32);
            uint2 u2 = *(const uint2*)(hw + (size_t)iv.z * 32);
            uint2 u3 = *(const uint2*)(hw + (size_t)iv.w * 32);
            float2 f;
            f = unpack2(u0.x); a0 += f.x; a1 += f.y;
            f = unpack2(u0.y); a2 += f.x; a3 += f.y;
            f = unpack2(u1.x); c0 += f.x; c1 += f.y;
            f = unpack2(u1.y); c2 += f.x; c3 += f.y;
            f = unpack2(u2.x); a0 += f.x; a1 += f.y;
            f = unpack2(u2.y); a2 += f.x; a3 += f.y;
            f = unpack2(u3.x); c0 += f.x; c1 += f.y;
            f = unpack2(u3.y); c2 += f.x; c3 += f.y;
        }
        for (; p < end; p += 4) {                          // padded tail, unmasked
            int i = csr_src[p + g];
            uint2 u = *(const uint2*)(hw + (size_t)i * 32);
            float2 f = unpack2(u.x); c0 += f.x; c1 += f.y;
            f = unpack2(u.y); c2 += f.x; c3 += f.y;
        }
        a0 += c0; a1 += c1; a2 += c2; a3 += c3;
        a0 += __shfl_xor(a0, 16); a0 += __shfl_xor(a0, 32);
        a1 += __shfl_xor(a1, 16); a1 += __shfl_xor(a1, 32);
        a2 += __shfl_xor(a2, 16); a2 += __shfl_xor(a2, 32);
        a3 += __shfl_xor(a3, 16); a3 += __shfl_xor(a3, 32);

        if (g == 0) {
            float o0, o1, o2, o3;
            if (LAYER == 1) {
                float4 bb = *(const float4*)(bias + 4 * w);
                o0 = fmaxf(fmaf(dn, a0, bb.x), 0.f) * dn;   // relu(a1+b1), prescale
                o1 = fmaxf(fmaf(dn, a1, bb.y), 0.f) * dn;
                o2 = fmaxf(fmaf(dn, a2, bb.z), 0.f) * dn;
                o3 = fmaxf(fmaf(dn, a3, bb.w), 0.f) * dn;
            } else {
                o0 = dn * a0; o1 = dn * a1; o2 = dn * a2; o3 = dn * a3;
            }
            uint2 ov;
            ov.x = f2h2(o0, o1);
            ov.y = f2h2(o2, o3);
            *(uint2*)(hout + (size_t)node * 32 + 2 * w) = ov;
        }
        if (!more) break;
        node = nxt;
        nt = ntn;
    }
}

// out[n][96] = a2[n][64] @ W2[64][96] + b2.  fp16 tile (+1 pad) in LDS,
// 4 outputs/thread.
__global__ __launch_bounds__(256) void gemm2(const unsigned* __restrict__ a2h,
                                             const float* __restrict__ W2,
                                             const float* __restrict__ b2,
                                             float* __restrict__ out, int n) {
    __shared__ unsigned w2[32 * OUT_F];     // [k2][j], 12 KiB
    __shared__ float bs[OUT_F];
    __shared__ unsigned tile[256 * 33];     // +1 word pad per row
    for (int t = threadIdx.x; t < 32 * OUT_F; t += 256) {
        int k2 = t / OUT_F, j = t - k2 * OUT_F;
        w2[t] = f2h2(W2[(2 * k2) * OUT_F + j], W2[(2 * k2 + 1) * OUT_F + j]);
    }
    for (int t = threadIdx.x; t < OUT_F; t += 256) bs[t] = b2[t];
    const int base = blockIdx.x * 256;
    const int rows = min(256, n - base);
    const uint4* srcv = (const uint4*)(a2h + (size_t)base * 32);
    const int nvec = rows * 8;
    for (int t = threadIdx.x; t < nvec; t += 256) {
        uint4 v = srcv[t];
        int r = t >> 3, w0 = (t & 7) * 4;
        unsigned* d = &tile[r * 33 + w0];
        d[0] = v.x; d[1] = v.y; d[2] = v.z; d[3] = v.w;
    }
    __syncthreads();
    const int total = rows * 24;
    for (int idx = threadIdx.x; idx < total; idx += 256) {
        int r = idx / 24, jq = idx - r * 24, j = jq * 4;
        float4 bb = *(const float4*)&bs[j];
        float acc0 = bb.x, acc1 = bb.y, acc2 = bb.z, acc3 = bb.w;
        const unsigned* tr = &tile[r * 33];
#pragma unroll
        for (int k2 = 0; k2 < 32; ++k2) {
            unsigned tv = tr[k2];
            uint4 wv = *(const uint4*)&w2[k2 * OUT_F + j];
            acc0 = fdot2u(tv, wv.x, acc0);
            acc1 = fdot2u(tv, wv.y, acc1);
            acc2 = fdot2u(tv, wv.z, acc2);
            acc3 = fdot2u(tv, wv.w, acc3);
        }
        *(float4*)(out + (size_t)(base + r) * OUT_F + j) =
            make_float4(acc0, acc1, acc2, acc3);
    }
}

extern "C" void kernel_launch(void* const* d_in, const int* in_sizes, int n_in,
                              void* d_out, int out_size, void* d_ws, size_t ws_size,
                              hipStream_t stream) {
    const float* x  = (const float*)d_in[0];
    const int*   ei = (const int*)d_in[1];
    const float* W1 = (const float*)d_in[2];
    const float* b1 = (const float*)d_in[3];
    const float* W2 = (const float*)d_in[4];
    const float* b2 = (const float*)d_in[5];
    float* out = (float*)d_out;

    const int n = in_sizes[0] / IN_F;          // 100000
    const int E = in_sizes[1] / 2;             // 1600000
    const int* src = ei;
    const int* dst = ei + E;
    const int nbuck  = (n + 255) >> 8;         // 391
    const int nchunk = (E + CHUNK - 1) / CHUNK;// 391
    const int M = nbuck * nchunk;              // 152881
    const int NBS = (M + 1023) / 1024;
    const int ntile = (n + 255) / 256;         // 391

    char* ws = (char*)d_ws;
    size_t off = 0;
    auto alloc = [&](size_t bytes) { void* p = ws + off; off = (off + bytes + 255) & ~(size_t)255; return p; };
    int*      hist    = (int*)alloc((size_t)M * 4);
    int*      offs    = (int*)alloc((size_t)M * 4);
    int*      bsum    = (int*)alloc(256 * 4);
    int*      boffs   = (int*)alloc(256 * 4);
    unsigned* part    = (unsigned*)alloc((size_t)E * 4);
    int*      csr_src = (int*)alloc(((size_t)E + (size_t)nbuck * 1024 + 64) * 4);
    int4*     nodetab = (int4*)alloc((size_t)n * 16);
    float*    dinv    = (float*)alloc((size_t)n * 4);
    unsigned* hs      = (unsigned*)alloc((size_t)(n + 1) * 32 * 4);
    unsigned* hs2     = (unsigned*)alloc((size_t)(n + 1) * 32 * 4);
    unsigned* a2h     = (unsigned*)alloc((size_t)n * 32 * 4);

    // CSR build: histogram -> scan -> partition -> per-bucket padded finalize
    init_sentinel<<<1, 64, 0, stream>>>(hs, hs2, n);
    hist_chunks <<<nchunk, 256, 0, stream>>>(dst, hist, E, nbuck, nchunk);
    scan_blocks <<<NBS, 256, 0, stream>>>(hist, offs, bsum, M);
    scan_bsums  <<<1, 256, 0, stream>>>(bsum, boffs, NBS);
    partition   <<<nchunk, 256, 0, stream>>>(src, dst, offs, boffs, part, E, nbuck, nchunk);
    build_bucket<<<nbuck, 256, 0, stream>>>(part, offs, boffs, csr_src, nodetab, dinv,
                                            n, E, nbuck, nchunk);

    // network
    gemm1      <<<2048, 256, 0, stream>>>(x, W1, dinv, hs, n);
    csr_agg<1> <<<AGG_BLOCKS, 256, 0, stream>>>(nodetab, csr_src, hs, b1, hs2, n);
    csr_agg<2> <<<AGG_BLOCKS, 256, 0, stream>>>(nodetab, csr_src, hs2, NULL, a2h, n);
    gemm2      <<<ntile, 256, 0, stream>>>(a2h, W2, b2, out, n);
}

// Round 10
// 189.400 us; speedup vs baseline: 2.5253x; 1.0384x over previous
//
#include <hip/hip_runtime.h>
#include <hip/hip_fp16.h>

// ConformalGCN: 2-layer GCN, N=100000, E=1600000 (+self loops).
// R9: csr_agg latency attack: rows padded to %16 (sentinel src=n, zero row)
//     -> no tail, no masks; 2 nodes per wave with interleaved branchless
//     chains (8 gathers in flight). Radix CSR build pads %16 (region b*4096).
//     gemm1/gemm2 (dot2) unchanged from R8.

#define IN_F  128
#define HID_F 64
#define OUT_F 96
#define CHUNK 4096
#define MAXB  12288         // stage capacity (padded bucket size), 48 KiB
#define AGG_BLOCKS 4096

typedef _Float16 f16x2 __attribute__((ext_vector_type(2)));

__device__ __forceinline__ float2 unpack2(unsigned u) {
    __half2 h = *reinterpret_cast<__half2*>(&u);
    return __half22float2(h);
}
__device__ __forceinline__ unsigned f2h2(float lo, float hi) {
    __half2 h = __floats2half2_rn(lo, hi);
    return *reinterpret_cast<unsigned*>(&h);
}

#if defined(__has_builtin)
#if __has_builtin(__builtin_amdgcn_fdot2)
#define HAS_FDOT2 1
#endif
#endif
#ifndef HAS_FDOT2
#define HAS_FDOT2 0
#endif

__device__ __forceinline__ float fdot2u(unsigned a, unsigned b, float c) {
#if HAS_FDOT2
    return __builtin_amdgcn_fdot2(__builtin_bit_cast(f16x2, a),
                                  __builtin_bit_cast(f16x2, b), c, false);
#else
    float2 fa = unpack2(a), fb = unpack2(b);
    return fmaf(fa.y, fb.y, fmaf(fa.x, fb.x, c));
#endif
}

// zero the sentinel feature rows hs[n], hs2[n]
__global__ __launch_bounds__(64) void init_sentinel(unsigned* __restrict__ hs,
                                                    unsigned* __restrict__ hs2, int n) {
    int t = threadIdx.x;
    if (t < 32) {
        hs[(size_t)n * 32 + t] = 0u;
        hs2[(size_t)n * 32 + t] = 0u;
    }
}

// ---- pass 1a: per-chunk bucket histograms (bucket-major layout) ----
__global__ __launch_bounds__(256) void hist_chunks(const int* __restrict__ dst,
                                                   int* __restrict__ hist,
                                                   int E, int nbuck, int nchunk) {
    __shared__ int cnt[512];
    for (int i = threadIdx.x; i < nbuck; i += 256) cnt[i] = 0;
    __syncthreads();
    const int base = blockIdx.x * CHUNK;
    const int lim = min(base + CHUNK, E);
    for (int e = base + threadIdx.x; e < lim; e += 256)
        atomicAdd(&cnt[dst[e] >> 8], 1);
    __syncthreads();
    for (int b = threadIdx.x; b < nbuck; b += 256)
        hist[b * nchunk + blockIdx.x] = cnt[b];
}

// ---- hierarchical exclusive prefix sum (1024 elems/block) ----
__global__ __launch_bounds__(256) void scan_blocks(const int* __restrict__ in,
                                                   int* __restrict__ pre,
                                                   int* __restrict__ bsum, int m) {
    __shared__ int lds[256];
    const int t = threadIdx.x;
    const int base = blockIdx.x * 1024 + t * 4;
    int v0 = (base + 0 < m) ? in[base + 0] : 0;
    int v1 = (base + 1 < m) ? in[base + 1] : 0;
    int v2 = (base + 2 < m) ? in[base + 2] : 0;
    int v3 = (base + 3 < m) ? in[base + 3] : 0;
    int s = v0 + v1 + v2 + v3;
    lds[t] = s;
    __syncthreads();
    for (int off = 1; off < 256; off <<= 1) {
        int add = (t >= off) ? lds[t - off] : 0;
        __syncthreads();
        lds[t] += add;
        __syncthreads();
    }
    int e = lds[t] - s;
    if (base + 0 < m) pre[base + 0] = e;
    e += v0;
    if (base + 1 < m) pre[base + 1] = e;
    e += v1;
    if (base + 2 < m) pre[base + 2] = e;
    e += v2;
    if (base + 3 < m) pre[base + 3] = e;
    if (t == 255) bsum[blockIdx.x] = lds[255];
}

__global__ __launch_bounds__(256) void scan_bsums(const int* __restrict__ bsum,
                                                  int* __restrict__ boffs, int nb) {
    __shared__ int lds[256];
    const int t = threadIdx.x;
    int v = (t < nb) ? bsum[t] : 0;
    lds[t] = v;
    __syncthreads();
    for (int off = 1; off < 256; off <<= 1) {
        int add = (t >= off) ? lds[t - off] : 0;
        __syncthreads();
        lds[t] += add;
        __syncthreads();
    }
    boffs[t] = lds[t] - v;
}

// ---- pass 1b: partition edges into bucket-grouped runs, 4B records ----
__global__ __launch_bounds__(256) void partition(const int* __restrict__ src,
                                                 const int* __restrict__ dst,
                                                 const int* __restrict__ offs,
                                                 const int* __restrict__ boffs,
                                                 unsigned* __restrict__ part,
                                                 int E, int nbuck, int nchunk) {
    __shared__ int off[512];
    for (int b = threadIdx.x; b < nbuck; b += 256) {
        int idx = b * nchunk + blockIdx.x;
        off[b] = offs[idx] + boffs[idx >> 10];
    }
    __syncthreads();
    const int base = blockIdx.x * CHUNK;
    const int lim = min(base + CHUNK, E);
    for (int e = base + threadIdx.x; e < lim; e += 256) {
        int d = dst[e], s = src[e];
        int pos = atomicAdd(&off[d >> 8], 1);
        part[pos] = ((unsigned)s << 8) | (unsigned)(d & 255);
    }
}

// ---- pass 2: per-bucket padded CSR finalize ----
// Padded row length = (deg+15)&~15, pad slots = sentinel src n (zero row).
// Bucket b's padded region starts at bstart + b*4096 (max pad 256*15 < 4096).
// Emits nodetab[node] = {beg, end_padded, dinv_bits, 0} and dinv[].
__global__ __launch_bounds__(256) void build_bucket(const unsigned* __restrict__ part,
                                                    const int* __restrict__ offs,
                                                    const int* __restrict__ boffs,
                                                    int* __restrict__ csr_src,
                                                    int4* __restrict__ nodetab,
                                                    float* __restrict__ dinv,
                                                    int n, int E, int nbuck, int nchunk) {
    __shared__ int cnt[256], sc[256], off[256];
    __shared__ int stage[MAXB];
    const int b = blockIdx.x;
    const int t = threadIdx.x;
    const int i0 = b * nchunk;
    const int bstart = offs[i0] + boffs[i0 >> 10];
    int bend = E;
    if (b + 1 < nbuck) {
        const int i1 = (b + 1) * nchunk;
        bend = offs[i1] + boffs[i1 >> 10];
    }
    const int bstart_pad = bstart + b * 4096;
    const int nodebase = b << 8;
    const int nnodes = min(256, n - nodebase);

    cnt[t] = 0;
    __syncthreads();
    for (int i = bstart + t; i < bend; i += 256)
        atomicAdd(&cnt[part[i] & 255u], 1);
    __syncthreads();
    const int deg = cnt[t];
    const int pdeg = (deg + 15) & ~15;
    sc[t] = pdeg;
    __syncthreads();
    for (int o = 1; o < 256; o <<= 1) {
        int add = (t >= o) ? sc[t - o] : 0;
        __syncthreads();
        sc[t] += add;
        __syncthreads();
    }
    const int pexcl = sc[t] - pdeg;
    const int psize = sc[255];
    if (t < nnodes) {
        float dv = rsqrtf((float)(deg + 1));   // +1 self loop
        nodetab[nodebase + t] = make_int4(bstart_pad + pexcl,
                                          bstart_pad + pexcl + pdeg,
                                          __float_as_int(dv), 0);
        dinv[nodebase + t] = dv;
    }
    off[t] = pexcl;
    __syncthreads();

    if (psize <= MAXB) {
        for (int i = t; i < psize; i += 256) stage[i] = n;   // sentinel fill
        __syncthreads();
        for (int i = bstart + t; i < bend; i += 256) {
            unsigned r = part[i];
            int pos = atomicAdd(&off[r & 255u], 1);
            stage[pos] = (int)(r >> 8);
        }
        __syncthreads();
        for (int i = t; i < psize; i += 256)
            csr_src[bstart_pad + i] = stage[i];
    } else {   // safety fallback
        for (int i = t; i < psize; i += 256) csr_src[bstart_pad + i] = n;
        __syncthreads();
        for (int i = bstart + t; i < bend; i += 256) {
            unsigned r = part[i];
            int pos = atomicAdd(&off[r & 255u], 1);
            csr_src[bstart_pad + pos] = (int)(r >> 8);
        }
    }
}

// hs[row] = fp16x2( dinv[row] * (x[row] @ W1) ).  2 rows/wave, dot2 inner.
__global__ __launch_bounds__(256) void gemm1(const float* __restrict__ x,
                                             const float* __restrict__ W1,
                                             const float* __restrict__ dinv,
                                             unsigned* __restrict__ hs, int n) {
    __shared__ unsigned w2[64 * HID_F];     // 16 KiB
    __shared__ uint2 xs2p[4][64];
    for (int t = threadIdx.x; t < 64 * HID_F; t += 256) {
        int k2 = t >> 6, col = t & 63;
        w2[t] = f2h2(W1[(2 * k2) * HID_F + col], W1[(2 * k2 + 1) * HID_F + col]);
    }
    __syncthreads();
    const int wave = threadIdx.x >> 6, lane = threadIdx.x & 63;
    const int npair = (n + 1) >> 1;
    for (int pr = blockIdx.x * 4 + wave; pr < npair; pr += gridDim.x * 4) {
        const int r0 = pr * 2, r1 = r0 + 1;
        const bool has1 = r1 < n;
        float2 v0 = *(const float2*)(x + (size_t)r0 * IN_F + lane * 2);
        float2 v1 = make_float2(0.f, 0.f);
        if (has1) v1 = *(const float2*)(x + (size_t)r1 * IN_F + lane * 2);
        xs2p[wave][lane] = make_uint2(f2h2(v0.x, v0.y), f2h2(v1.x, v1.y));
        float acc0 = 0.f, acc1 = 0.f;
#pragma unroll 8
        for (int k2 = 0; k2 < 64; ++k2) {
            uint2 xv = xs2p[wave][k2];
            unsigned wv = w2[k2 * 64 + lane];
            acc0 = fdot2u(xv.x, wv, acc0);
            acc1 = fdot2u(xv.y, wv, acc1);
        }
        acc0 *= dinv[r0];
        float o0 = __shfl_xor(acc0, 1);
        if (!(lane & 1)) hs[(size_t)r0 * 32 + (lane >> 1)] = f2h2(acc0, o0);
        if (has1) {
            acc1 *= dinv[r1];
            float o1 = __shfl_xor(acc1, 1);
            if (!(lane & 1)) hs[(size_t)r1 * 32 + (lane >> 1)] = f2h2(acc1, o1);
        }
    }
}

// Grid-stride; each wave owns TWO consecutive nodes with interleaved
// branchless gather chains (8 rows in flight).  Rows padded to %16 ->
// exact 16-edge iterations, no tail.  Quarter-wave slots as before.
template <int LAYER>
__global__ __launch_bounds__(256) void csr_agg(const int4* __restrict__ nodetab,
                                               const int* __restrict__ csr_src,
                                               const unsigned* __restrict__ hs,
                                               const float* __restrict__ bias,
                                               unsigned* __restrict__ hout, int n) {
    const int lane = threadIdx.x & 63;
    const int g = lane >> 4;          // edge slot 0..3
    const int w = lane & 15;          // feats 4w..4w+3
    const unsigned* __restrict__ hw = hs + 2 * w;
    const int STR = gridDim.x * 8;
    const int SENT = n;

    int nodeA = (blockIdx.x * 4 + (threadIdx.x >> 6)) * 2;
    if (nodeA >= n) return;
    int4 ntA = nodetab[nodeA];
    bool hasB = nodeA + 1 < n;
    int4 ntB = hasB ? nodetab[nodeA + 1] : make_int4(0, 0, 0, 0);

    for (;;) {
        const int nxt = nodeA + STR;
        const bool more = nxt < n;
        int4 ntA_n, ntB_n;
        bool hasB_n = false;
        if (more) {
            ntA_n = nodetab[nxt];
            hasB_n = nxt + 1 < n;
            if (hasB_n) ntB_n = nodetab[nxt + 1];
        }

        int pA = ntA.x;
        const int endA = ntA.y;
        const float dnA = __int_as_float(ntA.z);
        int pB = hasB ? ntB.x : 0;
        const int endB = hasB ? ntB.y : 0;
        const float dnB = hasB ? __int_as_float(ntB.z) : 0.f;

        float aA0 = 0.f, aA1 = 0.f, aA2 = 0.f, aA3 = 0.f;
        float cA0 = 0.f, cA1 = 0.f, cA2 = 0.f, cA3 = 0.f;
        float aB0 = 0.f, aB1 = 0.f, aB2 = 0.f, aB3 = 0.f;
        float cB0 = 0.f, cB1 = 0.f, cB2 = 0.f, cB3 = 0.f;
        if (g == 0) {                                      // self loops, once
            uint2 suA = *(const uint2*)(hw + (size_t)nodeA * 32);
            float2 s0 = unpack2(suA.x), s1 = unpack2(suA.y);
            aA0 = s0.x; aA1 = s0.y; aA2 = s1.x; aA3 = s1.y;
            if (hasB) {
                uint2 suB = *(const uint2*)(hw + (size_t)(nodeA + 1) * 32);
                float2 t0 = unpack2(suB.x), t1 = unpack2(suB.y);
                aB0 = t0.x; aB1 = t0.y; aB2 = t1.x; aB3 = t1.y;
            }
        }
        while (pA < endA || pB < endB) {
            int4 ivA = (pA < endA) ? *(const int4*)&csr_src[pA + 4 * g]
                                   : make_int4(SENT, SENT, SENT, SENT);
            int4 ivB = (pB < endB) ? *(const int4*)&csr_src[pB + 4 * g]
                                   : make_int4(SENT, SENT, SENT, SENT);
            uint2 uA0 = *(const uint2*)(hw + (size_t)ivA.x * 32);
            uint2 uA1 = *(const uint2*)(hw + (size_t)ivA.y * 32);
            uint2 uA2 = *(const uint2*)(hw + (size_t)ivA.z * 32);
            uint2 uA3 = *(const uint2*)(hw + (size_t)ivA.w * 32);
            uint2 uB0 = *(const uint2*)(hw + (size_t)ivB.x * 32);
            uint2 uB1 = *(const uint2*)(hw + (size_t)ivB.y * 32);
            uint2 uB2 = *(const uint2*)(hw + (size_t)ivB.z * 32);
            uint2 uB3 = *(const uint2*)(hw + (size_t)ivB.w * 32);
            float2 f;
            f = unpack2(uA0.x); aA0 += f.x; aA1 += f.y;
            f = unpack2(uA0.y); aA2 += f.x; aA3 += f.y;
            f = unpack2(uA1.x); cA0 += f.x; cA1 += f.y;
            f = unpack2(uA1.y); cA2 += f.x; cA3 += f.y;
            f = unpack2(uA2.x); aA0 += f.x; aA1 += f.y;
            f = unpack2(uA2.y); aA2 += f.x; aA3 += f.y;
            f = unpack2(uA3.x); cA0 += f.x; cA1 += f.y;
            f = unpack2(uA3.y); cA2 += f.x; cA3 += f.y;
            f = unpack2(uB0.x); aB0 += f.x; aB1 += f.y;
            f = unpack2(uB0.y); aB2 += f.x; aB3 += f.y;
            f = unpack2(uB1.x); cB0 += f.x; cB1 += f.y;
            f = unpack2(uB1.y); cB2 += f.x; cB3 += f.y;
            f = unpack2(uB2.x); aB0 += f.x; aB1 += f.y;
            f = unpack2(uB2.y); aB2 += f.x; aB3 += f.y;
            f = unpack2(uB3.x); cB0 += f.x; cB1 += f.y;
            f = unpack2(uB3.y); cB2 += f.x; cB3 += f.y;
            pA += 16; pB += 16;
        }
        aA0 += cA0; aA1 += cA1; aA2 += cA2; aA3 += cA3;
        aB0 += cB0; aB1 += cB1; aB2 += cB2; aB3 += cB3;
        aA0 += __shfl_xor(aA0, 16); aA0 += __shfl_xor(aA0, 32);
        aA1 += __shfl_xor(aA1, 16); aA1 += __shfl_xor(aA1, 32);
        aA2 += __shfl_xor(aA2, 16); aA2 += __shfl_xor(aA2, 32);
        aA3 += __shfl_xor(aA3, 16); aA3 += __shfl_xor(aA3, 32);
        aB0 += __shfl_xor(aB0, 16); aB0 += __shfl_xor(aB0, 32);
        aB1 += __shfl_xor(aB1, 16); aB1 += __shfl_xor(aB1, 32);
        aB2 += __shfl_xor(aB2, 16); aB2 += __shfl_xor(aB2, 32);
        aB3 += __shfl_xor(aB3, 16); aB3 += __shfl_xor(aB3, 32);

        if (g == 0) {
            float o0, o1, o2, o3;
            if (LAYER == 1) {
                float4 bb = *(const float4*)(bias + 4 * w);
                o0 = fmaxf(fmaf(dnA, aA0, bb.x), 0.f) * dnA;
                o1 = fmaxf(fmaf(dnA, aA1, bb.y), 0.f) * dnA;
                o2 = fmaxf(fmaf(dnA, aA2, bb.z), 0.f) * dnA;
                o3 = fmaxf(fmaf(dnA, aA3, bb.w), 0.f) * dnA;
            } else {
                o0 = dnA * aA0; o1 = dnA * aA1; o2 = dnA * aA2; o3 = dnA * aA3;
            }
            uint2 ov;
            ov.x = f2h2(o0, o1);
            ov.y = f2h2(o2, o3);
            *(uint2*)(hout + (size_t)nodeA * 32 + 2 * w) = ov;
            if (hasB) {
                if (LAYER == 1) {
                    float4 bb = *(const float4*)(bias + 4 * w);
                    o0 = fmaxf(fmaf(dnB, aB0, bb.x), 0.f) * dnB;
                    o1 = fmaxf(fmaf(dnB, aB1, bb.y), 0.f) * dnB;
                    o2 = fmaxf(fmaf(dnB, aB2, bb.z), 0.f) * dnB;
                    o3 = fmaxf(fmaf(dnB, aB3, bb.w), 0.f) * dnB;
                } else {
                    o0 = dnB * aB0; o1 = dnB * aB1; o2 = dnB * aB2; o3 = dnB * aB3;
                }
                ov.x = f2h2(o0, o1);
                ov.y = f2h2(o2, o3);
                *(uint2*)(hout + (size_t)(nodeA + 1) * 32 + 2 * w) = ov;
            }
        }
        if (!more) break;
        nodeA = nxt;
        ntA = ntA_n;
        hasB = hasB_n;
        ntB = ntB_n;
    }
}

// out[n][96] = a2[n][64] @ W2[64][96] + b2.  fp16 tile (+1 pad) in LDS,
// 4 outputs/thread.
__global__ __launch_bounds__(256) void gemm2(const unsigned* __restrict__ a2h,
                                             const float* __restrict__ W2,
                                             const float* __restrict__ b2,
                                             float* __restrict__ out, int n) {
    __shared__ unsigned w2[32 * OUT_F];     // [k2][j], 12 KiB
    __shared__ float bs[OUT_F];
    __shared__ unsigned tile[256 * 33];     // +1 word pad per row
    for (int t = threadIdx.x; t < 32 * OUT_F; t += 256) {
        int k2 = t / OUT_F, j = t - k2 * OUT_F;
        w2[t] = f2h2(W2[(2 * k2) * OUT_F + j], W2[(2 * k2 + 1) * OUT_F + j]);
    }
    for (int t = threadIdx.x; t < OUT_F; t += 256) bs[t] = b2[t];
    const int base = blockIdx.x * 256;
    const int rows = min(256, n - base);
    const uint4* srcv = (const uint4*)(a2h + (size_t)base * 32);
    const int nvec = rows * 8;
    for (int t = threadIdx.x; t < nvec; t += 256) {
        uint4 v = srcv[t];
        int r = t >> 3, w0 = (t & 7) * 4;
        unsigned* d = &tile[r * 33 + w0];
        d[0] = v.x; d[1] = v.y; d[2] = v.z; d[3] = v.w;
    }
    __syncthreads();
    const int total = rows * 24;
    for (int idx = threadIdx.x; idx < total; idx += 256) {
        int r = idx / 24, jq = idx - r * 24, j = jq * 4;
        float4 bb = *(const float4*)&bs[j];
        float acc0 = bb.x, acc1 = bb.y, acc2 = bb.z, acc3 = bb.w;
        const unsigned* tr = &tile[r * 33];
#pragma unroll
        for (int k2 = 0; k2 < 32; ++k2) {
            unsigned tv = tr[k2];
            uint4 wv = *(const uint4*)&w2[k2 * OUT_F + j];
            acc0 = fdot2u(tv, wv.x, acc0);
            acc1 = fdot2u(tv, wv.y, acc1);
            acc2 = fdot2u(tv, wv.z, acc2);
            acc3 = fdot2u(tv, wv.w, acc3);
        }
        *(float4*)(out + (size_t)(base + r) * OUT_F + j) =
            make_float4(acc0, acc1, acc2, acc3);
    }
}

extern "C" void kernel_launch(void* const* d_in, const int* in_sizes, int n_in,
                              void* d_out, int out_size, void* d_ws, size_t ws_size,
                              hipStream_t stream) {
    const float* x  = (const float*)d_in[0];
    const int*   ei = (const int*)d_in[1];
    const float* W1 = (const float*)d_in[2];
    const float* b1 = (const float*)d_in[3];
    const float* W2 = (const float*)d_in[4];
    const float* b2 = (const float*)d_in[5];
    float* out = (float*)d_out;

    const int n = in_sizes[0] / IN_F;          // 100000
    const int E = in_sizes[1] / 2;             // 1600000
    const int* src = ei;
    const int* dst = ei + E;
    const int nbuck  = (n + 255) >> 8;         // 391
    const int nchunk = (E + CHUNK - 1) / CHUNK;// 391
    const int M = nbuck * nchunk;              // 152881
    const int NBS = (M + 1023) / 1024;
    const int ntile = (n + 255) / 256;         // 391

    char* ws = (char*)d_ws;
    size_t off = 0;
    auto alloc = [&](size_t bytes) { void* p = ws + off; off = (off + bytes + 255) & ~(size_t)255; return p; };
    int*      hist    = (int*)alloc((size_t)M * 4);
    int*      offs    = (int*)alloc((size_t)M * 4);
    int*      bsum    = (int*)alloc(256 * 4);
    int*      boffs   = (int*)alloc(256 * 4);
    unsigned* part    = (unsigned*)alloc((size_t)E * 4);
    int*      csr_src = (int*)alloc(((size_t)E + (size_t)nbuck * 4096 + 64) * 4);
    int4*     nodetab = (int4*)alloc((size_t)n * 16);
    float*    dinv    = (float*)alloc((size_t)n * 4);
    unsigned* hs      = (unsigned*)alloc((size_t)(n + 1) * 32 * 4);
    unsigned* hs2     = (unsigned*)alloc((size_t)(n + 1) * 32 * 4);
    unsigned* a2h     = (unsigned*)alloc((size_t)n * 32 * 4);

    // CSR build: histogram -> scan -> partition -> per-bucket padded finalize
    init_sentinel<<<1, 64, 0, stream>>>(hs, hs2, n);
    hist_chunks <<<nchunk, 256, 0, stream>>>(dst, hist, E, nbuck, nchunk);
    scan_blocks <<<NBS, 256, 0, stream>>>(hist, offs, bsum, M);
    scan_bsums  <<<1, 256, 0, stream>>>(bsum, boffs, NBS);
    partition   <<<nchunk, 256, 0, stream>>>(src, dst, offs, boffs, part, E, nbuck, nchunk);
    build_bucket<<<nbuck, 256, 0, stream>>>(part, offs, boffs, csr_src, nodetab, dinv,
                                            n, E, nbuck, nchunk);

    // network
    gemm1      <<<2048, 256, 0, stream>>>(x, W1, dinv, hs, n);
    csr_agg<1> <<<AGG_BLOCKS, 256, 0, stream>>>(nodetab, csr_src, hs, b1, hs2, n);
    csr_agg<2> <<<AGG_BLOCKS, 256, 0, stream>>>(nodetab, csr_src, hs2, NULL, a2h, n);
    gemm2      <<<ntile, 256, 0, stream>>>(a2h, W2, b2, out, n);
}

// Round 11
// 186.339 us; speedup vs baseline: 2.5668x; 1.0164x over previous
//
#include <hip/hip_runtime.h>
#include <hip/hip_fp16.h>

// ConformalGCN: 2-layer GCN, N=100000, E=1600000 (+self loops).
// R10: (1) gemm1 4-rows-per-wave: broadcast uint4 x-stage -> 1 LDS clk/dot2
//      (was LDS-pipe-bound at 2 reads/2 dot2); (2) csr_agg accumulates via
//      fdot2 lane-extract masks (1,0)/(0,1): 1 VALU/feature vs cvt+add.
//      Padded %16 CSR + 2-node interleaved gather chains (R9) unchanged.

#define IN_F  128
#define HID_F 64
#define OUT_F 96
#define CHUNK 4096
#define MAXB  12288         // stage capacity (padded bucket size), 48 KiB
#define AGG_BLOCKS 4096
#define ONE_LO 0x00003C00u  // fp16 (1.0, 0.0)
#define ONE_HI 0x3C000000u  // fp16 (0.0, 1.0)

typedef _Float16 f16x2 __attribute__((ext_vector_type(2)));

__device__ __forceinline__ float2 unpack2(unsigned u) {
    __half2 h = *reinterpret_cast<__half2*>(&u);
    return __half22float2(h);
}
__device__ __forceinline__ unsigned f2h2(float lo, float hi) {
    __half2 h = __floats2half2_rn(lo, hi);
    return *reinterpret_cast<unsigned*>(&h);
}

#if defined(__has_builtin)
#if __has_builtin(__builtin_amdgcn_fdot2)
#define HAS_FDOT2 1
#endif
#endif
#ifndef HAS_FDOT2
#define HAS_FDOT2 0
#endif

__device__ __forceinline__ float fdot2u(unsigned a, unsigned b, float c) {
#if HAS_FDOT2
    return __builtin_amdgcn_fdot2(__builtin_bit_cast(f16x2, a),
                                  __builtin_bit_cast(f16x2, b), c, false);
#else
    float2 fa = unpack2(a), fb = unpack2(b);
    return fmaf(fa.y, fb.y, fmaf(fa.x, fb.x, c));
#endif
}

// zero the sentinel feature rows hs[n], hs2[n]
__global__ __launch_bounds__(64) void init_sentinel(unsigned* __restrict__ hs,
                                                    unsigned* __restrict__ hs2, int n) {
    int t = threadIdx.x;
    if (t < 32) {
        hs[(size_t)n * 32 + t] = 0u;
        hs2[(size_t)n * 32 + t] = 0u;
    }
}

// ---- pass 1a: per-chunk bucket histograms (bucket-major layout) ----
__global__ __launch_bounds__(256) void hist_chunks(const int* __restrict__ dst,
                                                   int* __restrict__ hist,
                                                   int E, int nbuck, int nchunk) {
    __shared__ int cnt[512];
    for (int i = threadIdx.x; i < nbuck; i += 256) cnt[i] = 0;
    __syncthreads();
    const int base = blockIdx.x * CHUNK;
    const int lim = min(base + CHUNK, E);
    for (int e = base + threadIdx.x; e < lim; e += 256)
        atomicAdd(&cnt[dst[e] >> 8], 1);
    __syncthreads();
    for (int b = threadIdx.x; b < nbuck; b += 256)
        hist[b * nchunk + blockIdx.x] = cnt[b];
}

// ---- hierarchical exclusive prefix sum (1024 elems/block) ----
__global__ __launch_bounds__(256) void scan_blocks(const int* __restrict__ in,
                                                   int* __restrict__ pre,
                                                   int* __restrict__ bsum, int m) {
    __shared__ int lds[256];
    const int t = threadIdx.x;
    const int base = blockIdx.x * 1024 + t * 4;
    int v0 = (base + 0 < m) ? in[base + 0] : 0;
    int v1 = (base + 1 < m) ? in[base + 1] : 0;
    int v2 = (base + 2 < m) ? in[base + 2] : 0;
    int v3 = (base + 3 < m) ? in[base + 3] : 0;
    int s = v0 + v1 + v2 + v3;
    lds[t] = s;
    __syncthreads();
    for (int off = 1; off < 256; off <<= 1) {
        int add = (t >= off) ? lds[t - off] : 0;
        __syncthreads();
        lds[t] += add;
        __syncthreads();
    }
    int e = lds[t] - s;
    if (base + 0 < m) pre[base + 0] = e;
    e += v0;
    if (base + 1 < m) pre[base + 1] = e;
    e += v1;
    if (base + 2 < m) pre[base + 2] = e;
    e += v2;
    if (base + 3 < m) pre[base + 3] = e;
    if (t == 255) bsum[blockIdx.x] = lds[255];
}

__global__ __launch_bounds__(256) void scan_bsums(const int* __restrict__ bsum,
                                                  int* __restrict__ boffs, int nb) {
    __shared__ int lds[256];
    const int t = threadIdx.x;
    int v = (t < nb) ? bsum[t] : 0;
    lds[t] = v;
    __syncthreads();
    for (int off = 1; off < 256; off <<= 1) {
        int add = (t >= off) ? lds[t - off] : 0;
        __syncthreads();
        lds[t] += add;
        __syncthreads();
    }
    boffs[t] = lds[t] - v;
}

// ---- pass 1b: partition edges into bucket-grouped runs, 4B records ----
__global__ __launch_bounds__(256) void partition(const int* __restrict__ src,
                                                 const int* __restrict__ dst,
                                                 const int* __restrict__ offs,
                                                 const int* __restrict__ boffs,
                                                 unsigned* __restrict__ part,
                                                 int E, int nbuck, int nchunk) {
    __shared__ int off[512];
    for (int b = threadIdx.x; b < nbuck; b += 256) {
        int idx = b * nchunk + blockIdx.x;
        off[b] = offs[idx] + boffs[idx >> 10];
    }
    __syncthreads();
    const int base = blockIdx.x * CHUNK;
    const int lim = min(base + CHUNK, E);
    for (int e = base + threadIdx.x; e < lim; e += 256) {
        int d = dst[e], s = src[e];
        int pos = atomicAdd(&off[d >> 8], 1);
        part[pos] = ((unsigned)s << 8) | (unsigned)(d & 255);
    }
}

// ---- pass 2: per-bucket padded CSR finalize ----
__global__ __launch_bounds__(256) void build_bucket(const unsigned* __restrict__ part,
                                                    const int* __restrict__ offs,
                                                    const int* __restrict__ boffs,
                                                    int* __restrict__ csr_src,
                                                    int4* __restrict__ nodetab,
                                                    float* __restrict__ dinv,
                                                    int n, int E, int nbuck, int nchunk) {
    __shared__ int cnt[256], sc[256], off[256];
    __shared__ int stage[MAXB];
    const int b = blockIdx.x;
    const int t = threadIdx.x;
    const int i0 = b * nchunk;
    const int bstart = offs[i0] + boffs[i0 >> 10];
    int bend = E;
    if (b + 1 < nbuck) {
        const int i1 = (b + 1) * nchunk;
        bend = offs[i1] + boffs[i1 >> 10];
    }
    const int bstart_pad = bstart + b * 4096;
    const int nodebase = b << 8;
    const int nnodes = min(256, n - nodebase);

    cnt[t] = 0;
    __syncthreads();
    for (int i = bstart + t; i < bend; i += 256)
        atomicAdd(&cnt[part[i] & 255u], 1);
    __syncthreads();
    const int deg = cnt[t];
    const int pdeg = (deg + 15) & ~15;
    sc[t] = pdeg;
    __syncthreads();
    for (int o = 1; o < 256; o <<= 1) {
        int add = (t >= o) ? sc[t - o] : 0;
        __syncthreads();
        sc[t] += add;
        __syncthreads();
    }
    const int pexcl = sc[t] - pdeg;
    const int psize = sc[255];
    if (t < nnodes) {
        float dv = rsqrtf((float)(deg + 1));   // +1 self loop
        nodetab[nodebase + t] = make_int4(bstart_pad + pexcl,
                                          bstart_pad + pexcl + pdeg,
                                          __float_as_int(dv), 0);
        dinv[nodebase + t] = dv;
    }
    off[t] = pexcl;
    __syncthreads();

    if (psize <= MAXB) {
        for (int i = t; i < psize; i += 256) stage[i] = n;   // sentinel fill
        __syncthreads();
        for (int i = bstart + t; i < bend; i += 256) {
            unsigned r = part[i];
            int pos = atomicAdd(&off[r & 255u], 1);
            stage[pos] = (int)(r >> 8);
        }
        __syncthreads();
        for (int i = t; i < psize; i += 256)
            csr_src[bstart_pad + i] = stage[i];
    } else {   // safety fallback
        for (int i = t; i < psize; i += 256) csr_src[bstart_pad + i] = n;
        __syncthreads();
        for (int i = bstart + t; i < bend; i += 256) {
            unsigned r = part[i];
            int pos = atomicAdd(&off[r & 255u], 1);
            csr_src[bstart_pad + pos] = (int)(r >> 8);
        }
    }
}

// hs[row] = fp16x2( dinv[row] * (x[row] @ W1) ).
// 4 rows per wave: xs4[k2] = uint4 of 4 rows' packed k-pairs (broadcast b128),
// w2 read b32 full-wave -> 4 dot2 per 2 LDS reads, 4 independent acc chains.
__global__ __launch_bounds__(256) void gemm1(const float* __restrict__ x,
                                             const float* __restrict__ W1,
                                             const float* __restrict__ dinv,
                                             unsigned* __restrict__ hs, int n) {
    __shared__ unsigned w2[64 * HID_F];     // 16 KiB [k2][col]
    __shared__ uint4 xs4[4][64];            // 4 KiB, per-wave 4-row stage
    for (int t = threadIdx.x; t < 64 * HID_F; t += 256) {
        int k2 = t >> 6, col = t & 63;
        w2[t] = f2h2(W1[(2 * k2) * HID_F + col], W1[(2 * k2 + 1) * HID_F + col]);
    }
    __syncthreads();
    const int wave = threadIdx.x >> 6, lane = threadIdx.x & 63;
    const int nquad = (n + 3) >> 2;
    for (int q = blockIdx.x * 4 + wave; q < nquad; q += gridDim.x * 4) {
        const int r0 = q * 4;
        const bool h1 = r0 + 1 < n, h2 = r0 + 2 < n, h3 = r0 + 3 < n;
        const float* xp = x + (size_t)r0 * IN_F + lane * 2;
        float2 v0 = *(const float2*)(xp);
        float2 v1 = h1 ? *(const float2*)(xp + IN_F)     : make_float2(0.f, 0.f);
        float2 v2 = h2 ? *(const float2*)(xp + 2 * IN_F) : make_float2(0.f, 0.f);
        float2 v3 = h3 ? *(const float2*)(xp + 3 * IN_F) : make_float2(0.f, 0.f);
        uint4 pk;
        pk.x = f2h2(v0.x, v0.y);
        pk.y = f2h2(v1.x, v1.y);
        pk.z = f2h2(v2.x, v2.y);
        pk.w = f2h2(v3.x, v3.y);
        xs4[wave][lane] = pk;
        float a0 = 0.f, a1 = 0.f, a2 = 0.f, a3 = 0.f;
#pragma unroll 8
        for (int k2 = 0; k2 < 64; ++k2) {
            uint4 xv = xs4[wave][k2];               // broadcast b128
            unsigned wv = w2[k2 * 64 + lane];       // full-wave b32
            a0 = fdot2u(xv.x, wv, a0);
            a1 = fdot2u(xv.y, wv, a1);
            a2 = fdot2u(xv.z, wv, a2);
            a3 = fdot2u(xv.w, wv, a3);
        }
        a0 *= dinv[r0];
        a1 *= h1 ? dinv[r0 + 1] : 0.f;
        a2 *= h2 ? dinv[r0 + 2] : 0.f;
        a3 *= h3 ? dinv[r0 + 3] : 0.f;
        float b0 = __shfl_xor(a0, 1);
        float b1v = __shfl_xor(a1, 1);
        float b2v = __shfl_xor(a2, 1);
        float b3v = __shfl_xor(a3, 1);
        if (!(lane & 1)) {
            int wd = lane >> 1;
            hs[(size_t)r0 * 32 + wd] = f2h2(a0, b0);
            if (h1) hs[(size_t)(r0 + 1) * 32 + wd] = f2h2(a1, b1v);
            if (h2) hs[(size_t)(r0 + 2) * 32 + wd] = f2h2(a2, b2v);
            if (h3) hs[(size_t)(r0 + 3) * 32 + wd] = f2h2(a3, b3v);
        }
    }
}

// Grid-stride; each wave owns TWO consecutive nodes with interleaved
// branchless gather chains.  Rows padded to %16.  Accumulation via fdot2
// lane-extract masks: 1 VALU per feature (fp32 accumulate, no precision loss).
#define ACC2(u, slo, shi) { slo = fdot2u(u, ONE_LO, slo); shi = fdot2u(u, ONE_HI, shi); }
template <int LAYER>
__global__ __launch_bounds__(256) void csr_agg(const int4* __restrict__ nodetab,
                                               const int* __restrict__ csr_src,
                                               const unsigned* __restrict__ hs,
                                               const float* __restrict__ bias,
                                               unsigned* __restrict__ hout, int n) {
    const int lane = threadIdx.x & 63;
    const int g = lane >> 4;          // edge slot 0..3
    const int w = lane & 15;          // feats 4w..4w+3
    const unsigned* __restrict__ hw = hs + 2 * w;
    const int STR = gridDim.x * 8;
    const int SENT = n;

    int nodeA = (blockIdx.x * 4 + (threadIdx.x >> 6)) * 2;
    if (nodeA >= n) return;
    int4 ntA = nodetab[nodeA];
    bool hasB = nodeA + 1 < n;
    int4 ntB = hasB ? nodetab[nodeA + 1] : make_int4(0, 0, 0, 0);

    for (;;) {
        const int nxt = nodeA + STR;
        const bool more = nxt < n;
        int4 ntA_n, ntB_n;
        bool hasB_n = false;
        if (more) {
            ntA_n = nodetab[nxt];
            hasB_n = nxt + 1 < n;
            if (hasB_n) ntB_n = nodetab[nxt + 1];
        }

        int pA = ntA.x;
        const int endA = ntA.y;
        const float dnA = __int_as_float(ntA.z);
        int pB = hasB ? ntB.x : 0;
        const int endB = hasB ? ntB.y : 0;
        const float dnB = hasB ? __int_as_float(ntB.z) : 0.f;

        float aA0 = 0.f, aA1 = 0.f, aA2 = 0.f, aA3 = 0.f;
        float cA0 = 0.f, cA1 = 0.f, cA2 = 0.f, cA3 = 0.f;
        float aB0 = 0.f, aB1 = 0.f, aB2 = 0.f, aB3 = 0.f;
        float cB0 = 0.f, cB1 = 0.f, cB2 = 0.f, cB3 = 0.f;
        if (g == 0) {                                      // self loops, once
            uint2 suA = *(const uint2*)(hw + (size_t)nodeA * 32);
            ACC2(suA.x, aA0, aA1);
            ACC2(suA.y, aA2, aA3);
            if (hasB) {
                uint2 suB = *(const uint2*)(hw + (size_t)(nodeA + 1) * 32);
                ACC2(suB.x, aB0, aB1);
                ACC2(suB.y, aB2, aB3);
            }
        }
        while (pA < endA || pB < endB) {
            int4 ivA = (pA < endA) ? *(const int4*)&csr_src[pA + 4 * g]
                                   : make_int4(SENT, SENT, SENT, SENT);
            int4 ivB = (pB < endB) ? *(const int4*)&csr_src[pB + 4 * g]
                                   : make_int4(SENT, SENT, SENT, SENT);
            uint2 uA0 = *(const uint2*)(hw + (size_t)ivA.x * 32);
            uint2 uA1 = *(const uint2*)(hw + (size_t)ivA.y * 32);
            uint2 uA2 = *(const uint2*)(hw + (size_t)ivA.z * 32);
            uint2 uA3 = *(const uint2*)(hw + (size_t)ivA.w * 32);
            uint2 uB0 = *(const uint2*)(hw + (size_t)ivB.x * 32);
            uint2 uB1 = *(const uint2*)(hw + (size_t)ivB.y * 32);
            uint2 uB2 = *(const uint2*)(hw + (size_t)ivB.z * 32);
            uint2 uB3 = *(const uint2*)(hw + (size_t)ivB.w * 32);
            ACC2(uA0.x, aA0, aA1); ACC2(uA0.y, aA2, aA3);
            ACC2(uA1.x, cA0, cA1); ACC2(uA1.y, cA2, cA3);
            ACC2(uA2.x, aA0, aA1); ACC2(uA2.y, aA2, aA3);
            ACC2(uA3.x, cA0, cA1); ACC2(uA3.y, cA2, cA3);
            ACC2(uB0.x, aB0, aB1); ACC2(uB0.y, aB2, aB3);
            ACC2(uB1.x, cB0, cB1); ACC2(uB1.y, cB2, cB3);
            ACC2(uB2.x, aB0, aB1); ACC2(uB2.y, aB2, aB3);
            ACC2(uB3.x, cB0, cB1); ACC2(uB3.y, cB2, cB3);
            pA += 16; pB += 16;
        }
        aA0 += cA0; aA1 += cA1; aA2 += cA2; aA3 += cA3;
        aB0 += cB0; aB1 += cB1; aB2 += cB2; aB3 += cB3;
        aA0 += __shfl_xor(aA0, 16); aA0 += __shfl_xor(aA0, 32);
        aA1 += __shfl_xor(aA1, 16); aA1 += __shfl_xor(aA1, 32);
        aA2 += __shfl_xor(aA2, 16); aA2 += __shfl_xor(aA2, 32);
        aA3 += __shfl_xor(aA3, 16); aA3 += __shfl_xor(aA3, 32);
        aB0 += __shfl_xor(aB0, 16); aB0 += __shfl_xor(aB0, 32);
        aB1 += __shfl_xor(aB1, 16); aB1 += __shfl_xor(aB1, 32);
        aB2 += __shfl_xor(aB2, 16); aB2 += __shfl_xor(aB2, 32);
        aB3 += __shfl_xor(aB3, 16); aB3 += __shfl_xor(aB3, 32);

        if (g == 0) {
            float o0, o1, o2, o3;
            if (LAYER == 1) {
                float4 bb = *(const float4*)(bias + 4 * w);
                o0 = fmaxf(fmaf(dnA, aA0, bb.x), 0.f) * dnA;
                o1 = fmaxf(fmaf(dnA, aA1, bb.y), 0.f) * dnA;
                o2 = fmaxf(fmaf(dnA, aA2, bb.z), 0.f) * dnA;
                o3 = fmaxf(fmaf(dnA, aA3, bb.w), 0.f) * dnA;
            } else {
                o0 = dnA * aA0; o1 = dnA * aA1; o2 = dnA * aA2; o3 = dnA * aA3;
            }
            uint2 ov;
            ov.x = f2h2(o0, o1);
            ov.y = f2h2(o2, o3);
            *(uint2*)(hout + (size_t)nodeA * 32 + 2 * w) = ov;
            if (hasB) {
                if (LAYER == 1) {
                    float4 bb = *(const float4*)(bias + 4 * w);
                    o0 = fmaxf(fmaf(dnB, aB0, bb.x), 0.f) * dnB;
                    o1 = fmaxf(fmaf(dnB, aB1, bb.y), 0.f) * dnB;
                    o2 = fmaxf(fmaf(dnB, aB2, bb.z), 0.f) * dnB;
                    o3 = fmaxf(fmaf(dnB, aB3, bb.w), 0.f) * dnB;
                } else {
                    o0 = dnB * aB0; o1 = dnB * aB1; o2 = dnB * aB2; o3 = dnB * aB3;
                }
                ov.x = f2h2(o0, o1);
                ov.y = f2h2(o2, o3);
                *(uint2*)(hout + (size_t)(nodeA + 1) * 32 + 2 * w) = ov;
            }
        }
        if (!more) break;
        nodeA = nxt;
        ntA = ntA_n;
        hasB = hasB_n;
        ntB = ntB_n;
    }
}

// out[n][96] = a2[n][64] @ W2[64][96] + b2.  fp16 tile (+1 pad) in LDS,
// 4 outputs/thread.
__global__ __launch_bounds__(256) void gemm2(const unsigned* __restrict__ a2h,
                                             const float* __restrict__ W2,
                                             const float* __restrict__ b2,
                                             float* __restrict__ out, int n) {
    __shared__ unsigned w2[32 * OUT_F];     // [k2][j], 12 KiB
    __shared__ float bs[OUT_F];
    __shared__ unsigned tile[256 * 33];     // +1 word pad per row
    for (int t = threadIdx.x; t < 32 * OUT_F; t += 256) {
        int k2 = t / OUT_F, j = t - k2 * OUT_F;
        w2[t] = f2h2(W2[(2 * k2) * OUT_F + j], W2[(2 * k2 + 1) * OUT_F + j]);
    }
    for (int t = threadIdx.x; t < OUT_F; t += 256) bs[t] = b2[t];
    const int base = blockIdx.x * 256;
    const int rows = min(256, n - base);
    const uint4* srcv = (const uint4*)(a2h + (size_t)base * 32);
    const int nvec = rows * 8;
    for (int t = threadIdx.x; t < nvec; t += 256) {
        uint4 v = srcv[t];
        int r = t >> 3, w0 = (t & 7) * 4;
        unsigned* d = &tile[r * 33 + w0];
        d[0] = v.x; d[1] = v.y; d[2] = v.z; d[3] = v.w;
    }
    __syncthreads();
    const int total = rows * 24;
    for (int idx = threadIdx.x; idx < total; idx += 256) {
        int r = idx / 24, jq = idx - r * 24, j = jq * 4;
        float4 bb = *(const float4*)&bs[j];
        float acc0 = bb.x, acc1 = bb.y, acc2 = bb.z, acc3 = bb.w;
        const unsigned* tr = &tile[r * 33];
#pragma unroll
        for (int k2 = 0; k2 < 32; ++k2) {
            unsigned tv = tr[k2];
            uint4 wv = *(const uint4*)&w2[k2 * OUT_F + j];
            acc0 = fdot2u(tv, wv.x, acc0);
            acc1 = fdot2u(tv, wv.y, acc1);
            acc2 = fdot2u(tv, wv.z, acc2);
            acc3 = fdot2u(tv, wv.w, acc3);
        }
        *(float4*)(out + (size_t)(base + r) * OUT_F + j) =
            make_float4(acc0, acc1, acc2, acc3);
    }
}

extern "C" void kernel_launch(void* const* d_in, const int* in_sizes, int n_in,
                              void* d_out, int out_size, void* d_ws, size_t ws_size,
                              hipStream_t stream) {
    const float* x  = (const float*)d_in[0];
    const int*   ei = (const int*)d_in[1];
    const float* W1 = (const float*)d_in[2];
    const float* b1 = (const float*)d_in[3];
    const float* W2 = (const float*)d_in[4];
    const float* b2 = (const float*)d_in[5];
    float* out = (float*)d_out;

    const int n = in_sizes[0] / IN_F;          // 100000
    const int E = in_sizes[1] / 2;             // 1600000
    const int* src = ei;
    const int* dst = ei + E;
    const int nbuck  = (n + 255) >> 8;         // 391
    const int nchunk = (E + CHUNK - 1) / CHUNK;// 391
    const int M = nbuck * nchunk;              // 152881
    const int NBS = (M + 1023) / 1024;
    const int ntile = (n + 255) / 256;         // 391

    char* ws = (char*)d_ws;
    size_t off = 0;
    auto alloc = [&](size_t bytes) { void* p = ws + off; off = (off + bytes + 255) & ~(size_t)255; return p; };
    int*      hist    = (int*)alloc((size_t)M * 4);
    int*      offs    = (int*)alloc((size_t)M * 4);
    int*      bsum    = (int*)alloc(256 * 4);
    int*      boffs   = (int*)alloc(256 * 4);
    unsigned* part    = (unsigned*)alloc((size_t)E * 4);
    int*      csr_src = (int*)alloc(((size_t)E + (size_t)nbuck * 4096 + 64) * 4);
    int4*     nodetab = (int4*)alloc((size_t)n * 16);
    float*    dinv    = (float*)alloc((size_t)n * 4);
    unsigned* hs      = (unsigned*)alloc((size_t)(n + 1) * 32 * 4);
    unsigned* hs2     = (unsigned*)alloc((size_t)(n + 1) * 32 * 4);
    unsigned* a2h     = (unsigned*)alloc((size_t)n * 32 * 4);

    // CSR build: histogram -> scan -> partition -> per-bucket padded finalize
    init_sentinel<<<1, 64, 0, stream>>>(hs, hs2, n);
    hist_chunks <<<nchunk, 256, 0, stream>>>(dst, hist, E, nbuck, nchunk);
    scan_blocks <<<NBS, 256, 0, stream>>>(hist, offs, bsum, M);
    scan_bsums  <<<1, 256, 0, stream>>>(bsum, boffs, NBS);
    partition   <<<nchunk, 256, 0, stream>>>(src, dst, offs, boffs, part, E, nbuck, nchunk);
    build_bucket<<<nbuck, 256, 0, stream>>>(part, offs, boffs, csr_src, nodetab, dinv,
                                            n, E, nbuck, nchunk);

    // network
    gemm1      <<<2048, 256, 0, stream>>>(x, W1, dinv, hs, n);
    csr_agg<1> <<<AGG_BLOCKS, 256, 0, stream>>>(nodetab, csr_src, hs, b1, hs2, n);
    csr_agg<2> <<<AGG_BLOCKS, 256, 0, stream>>>(nodetab, csr_src, hs2, NULL, a2h, n);
    gemm2      <<<ntile, 256, 0, stream>>>(a2h, W2, b2, out, n);
}